// Round 1
// 1457.074 us; speedup vs baseline: 1.5853x; 1.5853x over previous
//
#include <hip/hip_runtime.h>
#include <hip/hip_bf16.h>

typedef __hip_bfloat16 bf16;
typedef __bf16 bf16x8 __attribute__((ext_vector_type(8)));
typedef float f32x4 __attribute__((ext_vector_type(4)));

#define NB   128   // graphs
#define NPGX 40    // nodes per graph
#define NNODE 5120 // total nodes
#define NE   20000 // edges
#define LPX  512   // protein seq len
#define MAXNX 45

__device__ __forceinline__ float tofl(bf16 v) { return __bfloat162float(v); }
__device__ __forceinline__ float tofl(float v) { return v; }
__device__ __forceinline__ void stv(float* p, float v) { *p = v; }
__device__ __forceinline__ void stv(bf16* p, float v) { *p = __float2bfloat16(v); }

// fp32 -> bf16 bits, round-to-nearest-even
__device__ __forceinline__ ushort f2bf(float f) {
    uint x = __float_as_uint(f);
    uint r = (x + 0x7fffu + ((x >> 16) & 1u)) >> 16;
    return (ushort)r;
}

// ---------------- generic tiled GEMM (scalar fp32; kept for small GEMMs) ----------------
template <typename TA, typename TO, int ACT, bool GATHER>
__global__ __launch_bounds__(256) void gemm_k(
    const TA* __restrict__ A, const float* __restrict__ B, const float* __restrict__ bias,
    TO* __restrict__ C, int M, int N, int K, const int* __restrict__ tgt)
{
    __shared__ float sA[16][65];
    __shared__ float sB[16][65];
    const int m0 = blockIdx.x * 64;
    const int n0 = blockIdx.y * 64;
    const int t = threadIdx.x;
    const int tx = t & 15, ty = t >> 4;
    float acc[4][4] = {};
    for (int k0 = 0; k0 < K; k0 += 16) {
#pragma unroll
        for (int i = 0; i < 4; i++) {           // A tile 64x16
            int idx = t + i * 256;
            int mm = idx >> 4, kk = idx & 15;
            int k = k0 + kk;
            float v = 0.f;
            if (k < K) {
                long row = m0 + mm;
                if (GATHER) { int bb = (int)(row >> 9); int l = (int)(row & 511); row = (long)tgt[bb] * LPX + l; }
                v = tofl(A[row * (long)K + k]);
            }
            sA[kk][mm] = v;
        }
#pragma unroll
        for (int i = 0; i < 4; i++) {           // B tile 16x64
            int idx = t + i * 256;
            int kk = idx >> 6, nn = idx & 63;
            int k = k0 + kk;
            float v = 0.f;
            if (k < K) v = B[(long)k * N + n0 + nn];
            sB[kk][nn] = v;
        }
        __syncthreads();
#pragma unroll
        for (int kk = 0; kk < 16; kk++) {
            float a[4], b[4];
#pragma unroll
            for (int i = 0; i < 4; i++) a[i] = sA[kk][ty * 4 + i];
#pragma unroll
            for (int j = 0; j < 4; j++) b[j] = sB[kk][tx * 4 + j];
#pragma unroll
            for (int i = 0; i < 4; i++)
#pragma unroll
                for (int j = 0; j < 4; j++) acc[i][j] = fmaf(a[i], b[j], acc[i][j]);
        }
        __syncthreads();
    }
#pragma unroll
    for (int i = 0; i < 4; i++) {
        int m = m0 + ty * 4 + i;
#pragma unroll
        for (int j = 0; j < 4; j++) {
            int n = n0 + tx * 4 + j;
            float v = acc[i][j];
            if (bias) v += bias[n];
            if (ACT == 1) v = fmaxf(v, 0.f);
            else if (ACT == 2) v = tanhf(v);
            stv(&C[(long)m * N + n], v);
        }
    }
}

// ---------------- weight transpose + bf16 convert: out[n][k] = bf16(in[k][n]) ----------------
__global__ __launch_bounds__(256) void k_transp(const float* __restrict__ in,
                                                ushort* __restrict__ out, int K, int N) {
    __shared__ float s[32][33];
    int kt = blockIdx.x * 32, nt = blockIdx.y * 32;
    int t = threadIdx.x;
    int tn = t & 31, tk = t >> 5;  // tk in 0..7
#pragma unroll
    for (int i = 0; i < 4; i++)
        s[tk + i * 8][tn] = in[(long)(kt + tk + i * 8) * N + nt + tn];
    __syncthreads();
#pragma unroll
    for (int i = 0; i < 4; i++)
        out[(long)(nt + tk + i * 8) * K + kt + tn] = f2bf(s[tn][tk + i * 8]);
}

// ---------------- MFMA bf16 GEMM: C = act(A[M,K] @ BT[N,K]^T + bias) ----------------
// A: fp32 (converted to bf16 during staging; optional protein gather) or bf16 (ushort) row-major.
// BT: bf16 [N][K] row-major (pre-transposed weights). M % 128 == 0, N % 128 == 0, K % 32 == 0.
// Tile 128x128, 4 waves (2x2), each wave 64x64 via 4x4 mfma_f32_16x16x32_bf16 fragments.
template <typename TA, typename TO, int ACT, bool GATHER>
__global__ __launch_bounds__(256) void gemm_mfma(
    const TA* __restrict__ A, const ushort* __restrict__ BT, const float* __restrict__ bias,
    TO* __restrict__ C, int M, int N, int K, const int* __restrict__ tgt)
{
    __shared__ __align__(16) ushort sA[128][40];   // pad 40: row stride 80B = 5*16B
    __shared__ __align__(16) ushort sB[128][40];
    const int t = threadIdx.x;
    const int lane = t & 63;
    const int wave = t >> 6;
    const int wr = wave >> 1, wc = wave & 1;       // wave 2x2 grid
    const int m0 = blockIdx.x * 128;
    const int n0 = blockIdx.y * 128;
    const int fr = lane & 15;                      // fragment row/col
    const int kh = lane >> 4;                      // k-half-of-8 select (0..3)

    f32x4 acc[4][4] = {};

    for (int k0 = 0; k0 < K; k0 += 32) {
        // ---- stage A tile 128x32 -> bf16 LDS ----
        if constexpr (sizeof(TA) == 2) {
            const ushort* Ap = (const ushort*)A;
#pragma unroll
            for (int i = 0; i < 2; i++) {
                int linear = i * 2048 + t * 8;
                int row = linear >> 5, k = linear & 31;      // k in {0,8,16,24}
                long gr = m0 + row;
                uint4 v = *(const uint4*)(Ap + gr * (long)K + k0 + k);
                *(uint4*)&sA[row][k] = v;
            }
        } else {
            const float* Ap = (const float*)A;
#pragma unroll
            for (int i = 0; i < 4; i++) {
                int linear = i * 1024 + t * 4;
                int row = linear >> 5, k = linear & 31;      // k in {0,4,...,28}
                long gr = m0 + row;
                if (GATHER) { int bb = (int)(gr >> 9); gr = (long)tgt[bb] * LPX + (gr & 511); }
                float4 v = *(const float4*)(Ap + gr * (long)K + k0 + k);
                ushort4 h;
                h.x = f2bf(v.x); h.y = f2bf(v.y); h.z = f2bf(v.z); h.w = f2bf(v.w);
                *(ushort4*)&sA[row][k] = h;
            }
        }
        // ---- stage B tile 128x32 (BT rows = output cols) ----
#pragma unroll
        for (int i = 0; i < 2; i++) {
            int linear = i * 2048 + t * 8;
            int row = linear >> 5, k = linear & 31;
            uint4 v = *(const uint4*)(BT + (long)(n0 + row) * K + k0 + k);
            *(uint4*)&sB[row][k] = v;
        }
        __syncthreads();

        bf16x8 a[4], b[4];
#pragma unroll
        for (int mf = 0; mf < 4; mf++)
            a[mf] = *(const bf16x8*)&sA[wr * 64 + mf * 16 + fr][kh * 8];
#pragma unroll
        for (int nf = 0; nf < 4; nf++)
            b[nf] = *(const bf16x8*)&sB[wc * 64 + nf * 16 + fr][kh * 8];
#pragma unroll
        for (int mf = 0; mf < 4; mf++)
#pragma unroll
            for (int nf = 0; nf < 4; nf++)
                acc[mf][nf] = __builtin_amdgcn_mfma_f32_16x16x32_bf16(a[mf], b[nf], acc[mf][nf], 0, 0, 0);
        __syncthreads();
    }

    // ---- epilogue: D row = (lane>>4)*4 + r, col = lane&15 within each 16x16 fragment ----
#pragma unroll
    for (int mf = 0; mf < 4; mf++) {
#pragma unroll
        for (int nf = 0; nf < 4; nf++) {
            int coln = n0 + wc * 64 + nf * 16 + fr;
            float bv = bias ? bias[coln] : 0.f;
#pragma unroll
            for (int r = 0; r < 4; r++) {
                int row = m0 + wr * 64 + mf * 16 + kh * 4 + r;
                float v = acc[mf][nf][r] + bv;
                if (ACT == 1) v = fmaxf(v, 0.f);
                else if (ACT == 2) v = tanhf(v);
                stv(&C[(long)row * N + coln], v);
            }
        }
    }
}

// ---------------- GCN graph preprocessing ----------------
__global__ void k_count(const int* __restrict__ dst, int* __restrict__ cnt, int E) {
    int e = blockIdx.x * 256 + threadIdx.x;
    if (e < E) atomicAdd(&cnt[dst[e]], 1);
}

__global__ void k_scan(const int* __restrict__ cnt, int* __restrict__ row_start,
                       float* __restrict__ dinv, float* __restrict__ deginv, int n) {
    __shared__ int sd[1024];
    __shared__ int scarry;
    int t = threadIdx.x;
    if (t == 0) scarry = 0;
    __syncthreads();
    for (int base = 0; base < n; base += 1024) {
        int i = base + t;
        int v = (i < n) ? cnt[i] : 0;
        sd[t] = v;
        __syncthreads();
        for (int off = 1; off < 1024; off <<= 1) {
            int tmp = (t >= off) ? sd[t - off] : 0;
            __syncthreads();
            sd[t] += tmp;
            __syncthreads();
        }
        int carry = scarry;
        if (i < n) {
            row_start[i] = carry + sd[t] - v;
            float deg = (float)(v + 1);
            dinv[i] = rsqrtf(deg);
            deginv[i] = 1.f / deg;
        }
        __syncthreads();
        if (t == 1023) scarry = carry + sd[1023];
        __syncthreads();
    }
    if (t == 0) row_start[n] = scarry;
}

__global__ void k_fill(const int* __restrict__ src, const int* __restrict__ dst,
                       const int* __restrict__ row_start, int* __restrict__ cursor,
                       int* __restrict__ col, float* __restrict__ val,
                       const float* __restrict__ dinv, int E) {
    int e = blockIdx.x * 256 + threadIdx.x;
    if (e >= E) return;
    int d = dst[e], s = src[e];
    int p = atomicAdd(&cursor[d], 1);
    int idx = row_start[d] + p;
    col[idx] = s;
    val[idx] = dinv[s] * dinv[d];
}

// out[i,f] = relu( xw[i,f]/deg[i] + sum_e val*xw[col,f] + b[f] )
template <bool DENSE>
__global__ void k_agg(const float* __restrict__ xw, const float* __restrict__ deginv,
                      const int* __restrict__ row_start, const int* __restrict__ col,
                      const float* __restrict__ val, const float* __restrict__ bias,
                      float* __restrict__ out, int F) {
    int idx = blockIdx.x * 256 + threadIdx.x;
    if (idx >= NNODE * F) return;
    int i = idx / F, f = idx - i * F;
    float s = xw[idx] * deginv[i];
    int e0 = row_start[i], e1 = row_start[i + 1];
    for (int e = e0; e < e1; e++) s += val[e] * xw[col[e] * F + f];
    s += bias[f];
    s = fmaxf(s, 0.f);
    if (DENSE) {
        int g = i / NPGX, pos = i - g * NPGX;
        out[(g * MAXNX + pos) * F + f] = s;
    } else {
        out[idx] = s;
    }
}

// ---------------- co-attention ----------------
__global__ __launch_bounds__(256) void k_C(const bf16* __restrict__ tWb,
                                           const float* __restrict__ hd2, float* __restrict__ Cb) {
    int b = blockIdx.x, lt = blockIdx.y;
    __shared__ float sx[45][129];
    for (int t = threadIdx.x; t < 45 * 128; t += 256)
        sx[t >> 7][t & 127] = hd2[(b * 45 + (t >> 7)) * 128 + (t & 127)];
    __syncthreads();
    for (int t = threadIdx.x; t < 64 * 45; t += 256) {
        int ll = t / 45, s = t - ll * 45;
        int l = lt * 64 + ll;
        const bf16* arow = tWb + ((long)b * 512 + l) * 128;
        float a = 0.f;
        for (int m = 0; m < 128; m++) a += tofl(arow[m]) * sx[s][m];
        Cb[((long)b * 512 + l) * 45 + s] = tanhf(a);
    }
}

__global__ __launch_bounds__(256) void k_wcx(const float* __restrict__ Wc,
                                             const float* __restrict__ hd2, float* __restrict__ Wcx) {
    int b = blockIdx.x;
    __shared__ float sW[32][129];
    __shared__ float sx[45][129];
    for (int t = threadIdx.x; t < 32 * 128; t += 256) sW[t >> 7][t & 127] = Wc[t];
    for (int t = threadIdx.x; t < 45 * 128; t += 256)
        sx[t >> 7][t & 127] = hd2[(b * 45 + (t >> 7)) * 128 + (t & 127)];
    __syncthreads();
    for (int t = threadIdx.x; t < 32 * 45; t += 256) {
        int k = t / 45, s = t - k * 45;
        float a = 0.f;
        for (int m = 0; m < 128; m++) a += sW[k][m] * sx[s][m];
        Wcx[(b * 32 + k) * 45 + s] = a;
    }
}

__global__ __launch_bounds__(256) void k_wpt(const float* __restrict__ Wp,
                                             const bf16* __restrict__ t2, float* __restrict__ Wpt) {
    int b = blockIdx.x, lt = blockIdx.y;
    __shared__ float sW[32][129];
    __shared__ float sT[64][129];
    for (int t = threadIdx.x; t < 32 * 128; t += 256) sW[t >> 7][t & 127] = Wp[t];
    for (int t = threadIdx.x; t < 64 * 128; t += 256) {
        int l = t >> 7, m = t & 127;
        sT[l][m] = tofl(t2[((long)b * 512 + lt * 64 + l) * 128 + m]);
    }
    __syncthreads();
    for (int t = threadIdx.x; t < 32 * 64; t += 256) {
        int k = t >> 6, l = t & 63;
        float a = 0.f;
        for (int m = 0; m < 128; m++) a += sW[k][m] * sT[l][m];
        Wpt[((long)(b * 32 + k)) * 512 + lt * 64 + l] = a;
    }
}

__global__ __launch_bounds__(256) void k_hc(const float* __restrict__ Wpt,
                                            const float* __restrict__ Cb,
                                            const float* __restrict__ Wcx, float* __restrict__ Hc) {
    int b = blockIdx.x;
    __shared__ float sW[32][130];
    __shared__ float sC[128][46];
    float acc[6] = {0.f, 0.f, 0.f, 0.f, 0.f, 0.f};
    for (int lc = 0; lc < 4; lc++) {
        for (int t = threadIdx.x; t < 32 * 128; t += 256) {
            int k = t >> 7, l = t & 127;
            sW[k][l] = Wpt[((long)(b * 32 + k)) * 512 + lc * 128 + l];
        }
        for (int t = threadIdx.x; t < 128 * 45; t += 256) {
            int l = t / 45, s = t - l * 45;
            sC[l][s] = Cb[((long)b * 512 + lc * 128 + l) * 45 + s];
        }
        __syncthreads();
#pragma unroll
        for (int u = 0; u < 6; u++) {
            int o = threadIdx.x + u * 256;
            if (o < 32 * 45) {
                int k = o / 45, s = o - k * 45;
                float a = acc[u];
                for (int l = 0; l < 128; l++) a += sW[k][l] * sC[l][s];
                acc[u] = a;
            }
        }
        __syncthreads();
    }
    for (int u = 0; u < 6; u++) {
        int o = threadIdx.x + u * 256;
        if (o < 32 * 45) {
            int k = o / 45, s = o - k * 45;
            int idx = (b * 32 + k) * 45 + s;
            Hc[idx] = tanhf(Wcx[idx] + acc[u]);
        }
    }
}

__global__ __launch_bounds__(256) void k_hp(const float* __restrict__ Wcx,
                                            const float* __restrict__ Cb, float* __restrict__ Wpt) {
    int b = blockIdx.x;
    __shared__ float sW[32][46];
    for (int t = threadIdx.x; t < 32 * 45; t += 256) {
        int k = t / 45, s = t - k * 45;
        sW[k][s] = Wcx[b * 32 * 45 + t];
    }
    __syncthreads();
    for (int t = threadIdx.x; t < 32 * 512; t += 256) {
        int l = t >> 5, k = t & 31;
        const float* crow = Cb + ((long)b * 512 + l) * 45;
        float a = 0.f;
        for (int s = 0; s < 45; s++) a += sW[k][s] * crow[s];
        long idx = ((long)(b * 32 + k)) * 512 + l;
        Wpt[idx] = tanhf(Wpt[idx] + a);
    }
}

__global__ void k_ac(const float* __restrict__ whc, const float* __restrict__ Hc,
                     float* __restrict__ ac) {
    int b = blockIdx.x, s = threadIdx.x;  // 64 threads
    float logit = -1e30f;
    if (s < 45) {
        float a = 0.f;
        for (int k = 0; k < 32; k++) a += whc[k] * Hc[(b * 32 + k) * 45 + s];
        logit = a;
    }
    float m = logit;
    for (int off = 32; off; off >>= 1) m = fmaxf(m, __shfl_xor(m, off));
    float e = (s < 45) ? expf(logit - m) : 0.f;
    float sum = e;
    for (int off = 32; off; off >>= 1) sum += __shfl_xor(sum, off);
    if (s < 45) ac[b * 45 + s] = e / sum;
}

__global__ __launch_bounds__(256) void k_ap(const float* __restrict__ whp,
                                            const float* __restrict__ Hp, float* __restrict__ ap) {
    int b = blockIdx.x, t = threadIdx.x;
    float lv[2];
#pragma unroll
    for (int u = 0; u < 2; u++) {
        int l = t + u * 256;
        float a = 0.f;
        for (int k = 0; k < 32; k++) a += whp[k] * Hp[((long)(b * 32 + k)) * 512 + l];
        lv[u] = a;
    }
    __shared__ float wred[4];
    __shared__ float wsum[4];
    float m = fmaxf(lv[0], lv[1]);
    for (int off = 32; off; off >>= 1) m = fmaxf(m, __shfl_xor(m, off));
    if ((t & 63) == 0) wred[t >> 6] = m;
    __syncthreads();
    m = fmaxf(fmaxf(wred[0], wred[1]), fmaxf(wred[2], wred[3]));
    float e0 = expf(lv[0] - m), e1 = expf(lv[1] - m);
    float s = e0 + e1;
    for (int off = 32; off; off >>= 1) s += __shfl_xor(s, off);
    if ((t & 63) == 0) wsum[t >> 6] = s;
    __syncthreads();
    s = wsum[0] + wsum[1] + wsum[2] + wsum[3];
    ap[b * 512 + t] = e0 / s;
    ap[b * 512 + t + 256] = e1 / s;
}

__global__ void k_cp(const float* __restrict__ ac, const float* __restrict__ ap,
                     const float* __restrict__ hd2, const bf16* __restrict__ t2,
                     float* __restrict__ cp) {
    int b = blockIdx.x, m = threadIdx.x;  // 128 threads
    float c = 0.f;
    for (int s = 0; s < 45; s++) c += ac[b * 45 + s] * hd2[(b * 45 + s) * 128 + m];
    float p = 0.f;
    for (int l = 0; l < 512; l++) p += ap[b * 512 + l] * tofl(t2[((long)b * 512 + l) * 128 + m]);
    cp[b * 256 + m] = c;
    cp[b * 256 + 128 + m] = p;
}

__global__ void k_out(const float* __restrict__ c2o, const float* __restrict__ outW,
                      const float* __restrict__ outb, float* __restrict__ out) {
    int b = blockIdx.x, t = threadIdx.x;  // 64 threads
    float a = 0.f;
    for (int j = t; j < 512; j += 64) a += c2o[b * 512 + j] * outW[j];
    for (int off = 32; off; off >>= 1) a += __shfl_xor(a, off);
    if (t == 0) out[b] = a + outb[0];
}

extern "C" void kernel_launch(void* const* d_in, const int* in_sizes, int n_in,
                              void* d_out, int out_size, void* d_ws, size_t ws_size,
                              hipStream_t stream) {
    const float* x        = (const float*)d_in[0];
    const int*   ei       = (const int*)d_in[1];
    const int*   tgt      = (const int*)d_in[2];
    const float* proteins = (const float*)d_in[4];
    const float* gW1 = (const float*)d_in[5];  const float* gb1 = (const float*)d_in[6];
    const float* gW2 = (const float*)d_in[7];  const float* gb2 = (const float*)d_in[8];
    const float* gW3 = (const float*)d_in[9];  const float* gb3 = (const float*)d_in[10];
    const float* fc1_W = (const float*)d_in[11]; const float* fc1_b = (const float*)d_in[12];
    const float* fc2_W = (const float*)d_in[13]; const float* fc2_b = (const float*)d_in[14];
    const float* bert1_W = (const float*)d_in[15]; const float* bert1_b = (const float*)d_in[16];
    const float* bert2_W = (const float*)d_in[17]; const float* bert2_b = (const float*)d_in[18];
    const float* W_b = (const float*)d_in[19];
    const float* W_c = (const float*)d_in[20];
    const float* W_p = (const float*)d_in[21];
    const float* w_hc = (const float*)d_in[22];
    const float* w_hp = (const float*)d_in[23];
    const float* cat1_W = (const float*)d_in[24]; const float* cat1_b = (const float*)d_in[25];
    const float* cat2_W = (const float*)d_in[26]; const float* cat2_b = (const float*)d_in[27];
    const float* out_W = (const float*)d_in[28]; const float* out_b = (const float*)d_in[29];

    const int* src = ei;            // edge_index[0]
    const int* dst = ei + NE;       // edge_index[1]

    // ---- workspace layout (bump allocator, 256B aligned; total ~64 MiB) ----
    char* w = (char*)d_ws;
    auto alloc = [&](size_t bytes) -> void* {
        void* p = (void*)w;
        w += (bytes + 255) & ~(size_t)255;
        return p;
    };
    int*   cnt       = (int*)alloc(NNODE * 4);
    int*   row_start = (int*)alloc((NNODE + 1) * 4);
    int*   cursor    = (int*)alloc(NNODE * 4);
    int*   colv      = (int*)alloc(NE * 4);
    float* valv      = (float*)alloc(NE * 4);
    float* dinv      = (float*)alloc(NNODE * 4);
    float* deginv    = (float*)alloc(NNODE * 4);
    float* h_a       = (float*)alloc((size_t)NNODE * 256 * 4);  // 5.24MB (also Wpt alias start)
    float* h_b       = (float*)alloc((size_t)NNODE * 128 * 4);  // 2.62MB
    float* hd        = (float*)alloc((size_t)5760 * 256 * 4);   // 5.90MB (dense, zero-padded)
    bf16*  fc1o      = (bf16*)alloc((size_t)5760 * 1024 * 2);   // 11.80MB (aliased later by Cb)
    float* hd2       = (float*)alloc((size_t)5760 * 128 * 4);   // 2.95MB
    bf16*  t1        = (bf16*)alloc((size_t)65536 * 128 * 2);   // 16.78MB (aliased later by tWb)
    bf16*  t2        = (bf16*)alloc((size_t)65536 * 128 * 2);   // 16.78MB
    float* Wcx       = (float*)alloc((size_t)NB * 32 * 45 * 4);
    float* Hc        = (float*)alloc((size_t)NB * 32 * 45 * 4);
    float* ac        = (float*)alloc((size_t)NB * 45 * 4);
    float* ap        = (float*)alloc((size_t)NB * 512 * 4);
    float* cp        = (float*)alloc((size_t)NB * 256 * 4);
    float* c1o       = (float*)alloc((size_t)NB * 1024 * 4);
    float* c2o       = (float*)alloc((size_t)NB * 512 * 4);
    // pre-transposed bf16 weights for MFMA GEMMs ([N][K] layout)
    ushort* fc1_WT   = (ushort*)alloc((size_t)1024 * 256 * 2);
    ushort* fc2_WT   = (ushort*)alloc((size_t)128 * 1024 * 2);
    ushort* bert1_WT = (ushort*)alloc((size_t)128 * 1280 * 2);
    ushort* bert2_WT = (ushort*)alloc((size_t)128 * 128 * 2);
    ushort* W_bT     = (ushort*)alloc((size_t)128 * 128 * 2);
    // aliases (lifetimes disjoint):
    bf16*  tWb = t1;                     // t1 dead after bert2
    float* Cb  = (float*)fc1o;           // fc1o dead after fc2; 11,796,480 B == fc1o bytes
    float* Wpt = h_a;                    // 8.39MB spans h_a+h_b+0.53MB of hd; all dead by k_wpt

    // ---- weight transposes (independent; run first) ----
    k_transp<<<dim3(8, 32), 256, 0, stream>>>(fc1_W, fc1_WT, 256, 1024);
    k_transp<<<dim3(32, 4), 256, 0, stream>>>(fc2_W, fc2_WT, 1024, 128);
    k_transp<<<dim3(40, 4), 256, 0, stream>>>(bert1_W, bert1_WT, 1280, 128);
    k_transp<<<dim3(4, 4), 256, 0, stream>>>(bert2_W, bert2_WT, 128, 128);
    k_transp<<<dim3(4, 4), 256, 0, stream>>>(W_b, W_bT, 128, 128);

    // ---- graph preprocessing ----
    hipMemsetAsync(cnt, 0, NNODE * 4, stream);
    hipMemsetAsync(cursor, 0, NNODE * 4, stream);
    hipMemsetAsync(hd, 0, (size_t)5760 * 256 * 4, stream);
    k_count<<<(NE + 255) / 256, 256, 0, stream>>>(dst, cnt, NE);
    k_scan<<<1, 1024, 0, stream>>>(cnt, row_start, dinv, deginv, NNODE);
    k_fill<<<(NE + 255) / 256, 256, 0, stream>>>(src, dst, row_start, cursor, colv, valv, dinv, NE);

    // ---- GCN stack (fp32 scalar; small) ----
    gemm_k<float, float, 0, false><<<dim3(NNODE / 64, 2), 256, 0, stream>>>(x, gW1, nullptr, h_a, NNODE, 128, 78, nullptr);
    k_agg<false><<<(NNODE * 128 + 255) / 256, 256, 0, stream>>>(h_a, deginv, row_start, colv, valv, gb1, h_b, 128);
    gemm_k<float, float, 0, false><<<dim3(NNODE / 64, 2), 256, 0, stream>>>(h_b, gW2, nullptr, h_a, NNODE, 128, 128, nullptr);
    k_agg<false><<<(NNODE * 128 + 255) / 256, 256, 0, stream>>>(h_a, deginv, row_start, colv, valv, gb2, h_b, 128);
    gemm_k<float, float, 0, false><<<dim3(NNODE / 64, 4), 256, 0, stream>>>(h_b, gW3, nullptr, h_a, NNODE, 256, 128, nullptr);
    k_agg<true><<<(NNODE * 256 + 255) / 256, 256, 0, stream>>>(h_a, deginv, row_start, colv, valv, gb3, hd, 256);

    // ---- dense graph MLP (MFMA) ----
    gemm_mfma<float, bf16, 1, false><<<dim3(45, 8), 256, 0, stream>>>(hd, fc1_WT, fc1_b, fc1o, 5760, 1024, 256, nullptr);
    gemm_mfma<ushort, float, 1, false><<<dim3(45, 1), 256, 0, stream>>>((const ushort*)fc1o, fc2_WT, fc2_b, hd2, 5760, 128, 1024, nullptr);

    // ---- protein branch (MFMA; gather fused into bert1 A-staging) ----
    gemm_mfma<float, bf16, 1, true><<<dim3(512, 1), 256, 0, stream>>>(proteins, bert1_WT, bert1_b, t1, 65536, 128, 1280, tgt);
    gemm_mfma<ushort, bf16, 1, false><<<dim3(512, 1), 256, 0, stream>>>((const ushort*)t1, bert2_WT, bert2_b, t2, 65536, 128, 128, nullptr);
    gemm_mfma<ushort, bf16, 0, false><<<dim3(512, 1), 256, 0, stream>>>((const ushort*)t2, W_bT, nullptr, tWb, 65536, 128, 128, nullptr);

    // ---- co-attention ----
    k_C<<<dim3(NB, 8), 256, 0, stream>>>(tWb, hd2, Cb);
    k_wcx<<<NB, 256, 0, stream>>>(W_c, hd2, Wcx);
    k_wpt<<<dim3(NB, 8), 256, 0, stream>>>(W_p, t2, Wpt);
    k_hc<<<NB, 256, 0, stream>>>(Wpt, Cb, Wcx, Hc);
    k_hp<<<NB, 256, 0, stream>>>(Wcx, Cb, Wpt);     // Hp in-place
    k_ac<<<NB, 64, 0, stream>>>(w_hc, Hc, ac);
    k_ap<<<NB, 256, 0, stream>>>(w_hp, Wpt, ap);
    k_cp<<<NB, 128, 0, stream>>>(ac, ap, hd2, t2, cp);

    // ---- head MLP ----
    gemm_k<float, float, 1, false><<<dim3(2, 16), 256, 0, stream>>>(cp, cat1_W, cat1_b, c1o, 128, 1024, 256, nullptr);
    gemm_k<float, float, 1, false><<<dim3(2, 8), 256, 0, stream>>>(c1o, cat2_W, cat2_b, c2o, 128, 512, 1024, nullptr);
    k_out<<<NB, 64, 0, stream>>>(c2o, out_W, out_b, (float*)d_out);
}

// Round 3
// 1270.978 us; speedup vs baseline: 1.8174x; 1.1464x over previous
//
#include <hip/hip_runtime.h>
#include <hip/hip_bf16.h>

typedef __hip_bfloat16 bf16;
typedef __bf16 bf16x8 __attribute__((ext_vector_type(8)));
typedef float f32x4 __attribute__((ext_vector_type(4)));

#define NB   128   // graphs
#define NPGX 40    // nodes per graph
#define NNODE 5120 // total nodes
#define NE   20000 // edges
#define LPX  512   // protein seq len
#define MAXNX 45

__device__ __forceinline__ void stv(float* p, float v) { *p = v; }
__device__ __forceinline__ void stv(bf16* p, float v) { *p = __float2bfloat16(v); }
// fp32 -> bf16 bits, round-to-nearest-even
__device__ __forceinline__ ushort f2bf(float f) {
    uint x = __float_as_uint(f);
    return (ushort)((x + 0x7fffu + ((x >> 16) & 1u)) >> 16);
}
__device__ __forceinline__ float bf2f(ushort u) { return __uint_as_float(((uint)u) << 16); }

// ---------------- MFMA bf16 GEMM: C = act(A[M,K] @ BT[N,K]^T + bias) ----------------
// A: fp32 (converted to bf16 during staging; optional protein gather) or bf16 (ushort) row-major.
// BT: bf16 [N][K] row-major (pre-transposed weights). M % 128 == 0, N % 128 == 0, K % 32 == 0.
// Tile 128x128, 4 waves (2x2), each wave 64x64 via 4x4 mfma_f32_16x16x32_bf16 fragments.
template <typename TA, typename TO, int ACT, bool GATHER>
__global__ __launch_bounds__(256) void gemm_mfma(
    const TA* __restrict__ A, const ushort* __restrict__ BT, const float* __restrict__ bias,
    TO* __restrict__ C, int M, int N, int K, const int* __restrict__ tgt)
{
    __shared__ __align__(16) ushort sA[128][40];   // pad 40: row stride 80B
    __shared__ __align__(16) ushort sB[128][40];
    const int t = threadIdx.x;
    const int lane = t & 63;
    const int wave = t >> 6;
    const int wr = wave >> 1, wc = wave & 1;
    const int m0 = blockIdx.x * 128;
    const int n0 = blockIdx.y * 128;
    const int fr = lane & 15;
    const int kh = lane >> 4;

    f32x4 acc[4][4] = {};

    for (int k0 = 0; k0 < K; k0 += 32) {
        if constexpr (sizeof(TA) == 2) {
            const ushort* Ap = (const ushort*)A;
#pragma unroll
            for (int i = 0; i < 2; i++) {
                int linear = i * 2048 + t * 8;
                int row = linear >> 5, k = linear & 31;
                long gr = m0 + row;
                uint4 v = *(const uint4*)(Ap + gr * (long)K + k0 + k);
                *(uint4*)&sA[row][k] = v;
            }
        } else {
            const float* Ap = (const float*)A;
#pragma unroll
            for (int i = 0; i < 4; i++) {
                int linear = i * 1024 + t * 4;
                int row = linear >> 5, k = linear & 31;
                long gr = m0 + row;
                if (GATHER) { int bb = (int)(gr >> 9); gr = (long)tgt[bb] * LPX + (gr & 511); }
                float4 v = *(const float4*)(Ap + gr * (long)K + k0 + k);
                ushort4 h;
                h.x = f2bf(v.x); h.y = f2bf(v.y); h.z = f2bf(v.z); h.w = f2bf(v.w);
                *(ushort4*)&sA[row][k] = h;
            }
        }
#pragma unroll
        for (int i = 0; i < 2; i++) {
            int linear = i * 2048 + t * 8;
            int row = linear >> 5, k = linear & 31;
            uint4 v = *(const uint4*)(BT + (long)(n0 + row) * K + k0 + k);
            *(uint4*)&sB[row][k] = v;
        }
        __syncthreads();

        bf16x8 a[4], b[4];
#pragma unroll
        for (int mf = 0; mf < 4; mf++)
            a[mf] = *(const bf16x8*)&sA[wr * 64 + mf * 16 + fr][kh * 8];
#pragma unroll
        for (int nf = 0; nf < 4; nf++)
            b[nf] = *(const bf16x8*)&sB[wc * 64 + nf * 16 + fr][kh * 8];
#pragma unroll
        for (int mf = 0; mf < 4; mf++)
#pragma unroll
            for (int nf = 0; nf < 4; nf++)
                acc[mf][nf] = __builtin_amdgcn_mfma_f32_16x16x32_bf16(a[mf], b[nf], acc[mf][nf], 0, 0, 0);
        __syncthreads();
    }

#pragma unroll
    for (int mf = 0; mf < 4; mf++) {
#pragma unroll
        for (int nf = 0; nf < 4; nf++) {
            int coln = n0 + wc * 64 + nf * 16 + fr;
            float bv = bias ? bias[coln] : 0.f;
#pragma unroll
            for (int r = 0; r < 4; r++) {
                int row = m0 + wr * 64 + mf * 16 + kh * 4 + r;
                float v = acc[mf][nf][r] + bv;
                if (ACT == 1) v = fmaxf(v, 0.f);
                else if (ACT == 2) v = tanhf(v);
                stv(&C[(long)row * N + coln], v);
            }
        }
    }
}

// ---------------- all 5 weight transposes in ONE dispatch ----------------
// out[n][k] = bf16(in[k][n]); 32x32 tiles, 256 threads.
__global__ __launch_bounds__(256) void k_transp_all(
    const float* __restrict__ s0, const float* __restrict__ s1, const float* __restrict__ s2,
    const float* __restrict__ s3, const float* __restrict__ s4,
    ushort* __restrict__ d0, ushort* __restrict__ d1, ushort* __restrict__ d2,
    ushort* __restrict__ d3, ushort* __restrict__ d4)
{
    __shared__ float s[32][33];
    int bid = blockIdx.x;
    const float* in; ushort* out; int K, N, b;
    if (bid < 256)      { in = s0; out = d0; K = 256;  N = 1024; b = bid; }        // fc1_W  8x32
    else if (bid < 384) { in = s1; out = d1; K = 1024; N = 128;  b = bid - 256; }  // fc2_W  32x4
    else if (bid < 544) { in = s2; out = d2; K = 1280; N = 128;  b = bid - 384; }  // bert1  40x4
    else if (bid < 560) { in = s3; out = d3; K = 128;  N = 128;  b = bid - 544; }  // bert2  4x4
    else                { in = s4; out = d4; K = 128;  N = 128;  b = bid - 560; }  // W_b    4x4
    int ktiles = K / 32;
    int kt = (b % ktiles) * 32, nt = (b / ktiles) * 32;
    int t = threadIdx.x;
    int tn = t & 31, tk = t >> 5;
#pragma unroll
    for (int i = 0; i < 4; i++)
        s[tk + i * 8][tn] = in[(long)(kt + tk + i * 8) * N + nt + tn];
    __syncthreads();
#pragma unroll
    for (int i = 0; i < 4; i++)
        out[(long)(nt + tk + i * 8) * K + kt + tn] = f2bf(s[tn][tk + i * 8]);
}

// ---------------- GCN graph preprocessing ----------------
__global__ void k_count(const int* __restrict__ dst, int* __restrict__ cnt, int E) {
    int e = blockIdx.x * 256 + threadIdx.x;
    if (e < E) atomicAdd(&cnt[dst[e]], 1);
}

__global__ void k_scan(const int* __restrict__ cnt, int* __restrict__ row_start,
                       float* __restrict__ dinv, float* __restrict__ deginv, int n) {
    __shared__ int sd[1024];
    __shared__ int scarry;
    int t = threadIdx.x;
    if (t == 0) scarry = 0;
    __syncthreads();
    for (int base = 0; base < n; base += 1024) {
        int i = base + t;
        int v = (i < n) ? cnt[i] : 0;
        sd[t] = v;
        __syncthreads();
        for (int off = 1; off < 1024; off <<= 1) {
            int tmp = (t >= off) ? sd[t - off] : 0;
            __syncthreads();
            sd[t] += tmp;
            __syncthreads();
        }
        int carry = scarry;
        if (i < n) {
            row_start[i] = carry + sd[t] - v;
            float deg = (float)(v + 1);
            dinv[i] = rsqrtf(deg);
            deginv[i] = 1.f / deg;
        }
        __syncthreads();
        if (t == 1023) scarry = carry + sd[1023];
        __syncthreads();
    }
    if (t == 0) row_start[n] = scarry;
}

__global__ void k_fill(const int* __restrict__ src, const int* __restrict__ dst,
                       const int* __restrict__ row_start, int* __restrict__ cursor,
                       int* __restrict__ col, float* __restrict__ val,
                       const float* __restrict__ dinv, int E) {
    int e = blockIdx.x * 256 + threadIdx.x;
    if (e >= E) return;
    int d = dst[e], s = src[e];
    int p = atomicAdd(&cursor[d], 1);
    int idx = row_start[d] + p;
    col[idx] = s;
    val[idx] = dinv[s] * dinv[d];
}

// ---------------- fully fused 3-layer GCN, one block per graph ----------------
// hin: layer input (<=128 wide). hout: gemm result (<=256 wide). sW: 32-row weight k-tile.
__device__ __forceinline__ void gcn_gemm(const float (*hin)[132], float (*hout)[260],
                                         float (*sW)[260], const float* __restrict__ Wg,
                                         int K, int N, int NQ, int t) {
    f32x4 acc[10] = {};   // NQ <= 10
    for (int k0 = 0; k0 < K; k0 += 32) {
        int kmax = min(32, K - k0);
        __syncthreads();
        for (int o = t; o < kmax * N; o += 256) sW[o / N][o % N] = Wg[(k0 + o / N) * N + o % N];
        __syncthreads();
        for (int kk = 0; kk < kmax; kk++) {
#pragma unroll 10
            for (int j = 0; j < NQ; j++) {
                int q = t + j * 256;
                int i = q / (N / 4), f = (q % (N / 4)) * 4;
                float h = hin[i][k0 + kk];
                f32x4 wv = *(const f32x4*)&sW[kk][f];
                acc[j][0] += h * wv[0]; acc[j][1] += h * wv[1];
                acc[j][2] += h * wv[2]; acc[j][3] += h * wv[3];
            }
        }
    }
    __syncthreads();
#pragma unroll 10
    for (int j = 0; j < NQ; j++) {
        int q = t + j * 256;
        int i = q / (N / 4), f = (q % (N / 4)) * 4;
        *(f32x4*)&hout[i][f] = acc[j];
    }
}

__device__ __forceinline__ void gcn_agg(const float (*hout)[260], float (*hin)[132],
                                        const float* __restrict__ bias,
                                        const float* __restrict__ deginv,
                                        const int* __restrict__ row_start,
                                        const int* __restrict__ col,
                                        const float* __restrict__ val,
                                        float* __restrict__ hd, int N, bool tohd, int g, int t) {
    int base = g * NPGX;
    for (int o = t; o < 40 * N; o += 256) {
        int i = o / N, f = o - i * N;
        float s = hout[i][f] * deginv[base + i];
        int e0 = row_start[base + i], e1 = row_start[base + i + 1];
        for (int e = e0; e < e1; e++) s += val[e] * hout[col[e] - base][f];
        s += bias[f];
        s = fmaxf(s, 0.f);
        if (tohd) hd[(g * MAXNX + i) * N + f] = s;
        else      hin[i][f] = s;
    }
    if (tohd) for (int o = t; o < 5 * N; o += 256) hd[(g * MAXNX + 40) * N + o] = 0.f;
}

__global__ __launch_bounds__(256) void k_gcn(
    const float* __restrict__ x,
    const float* __restrict__ W1, const float* __restrict__ b1,
    const float* __restrict__ W2, const float* __restrict__ b2,
    const float* __restrict__ W3, const float* __restrict__ b3,
    const float* __restrict__ deginv, const int* __restrict__ row_start,
    const int* __restrict__ col, const float* __restrict__ val,
    float* __restrict__ hd)
{
    int g = blockIdx.x, t = threadIdx.x;
    __shared__ float hin[40][132];
    __shared__ float hout[40][260];
    __shared__ float sW[32][260];
    // preload x rows (40 x 78)
    for (int o = t; o < 40 * 78; o += 256) hin[o / 78][o % 78] = x[(g * NPGX + o / 78) * 78 + o % 78];
    // layer 1: K=78 N=128
    gcn_gemm(hin, hout, sW, W1, 78, 128, 5, t);
    __syncthreads();
    gcn_agg(hout, hin, b1, deginv, row_start, col, val, nullptr, 128, false, g, t);
    __syncthreads();
    // layer 2: K=128 N=128
    gcn_gemm(hin, hout, sW, W2, 128, 128, 5, t);
    __syncthreads();
    gcn_agg(hout, hin, b2, deginv, row_start, col, val, nullptr, 128, false, g, t);
    __syncthreads();
    // layer 3: K=128 N=256, aggregate directly into dense hd (incl. zero pad rows)
    gcn_gemm(hin, hout, sW, W3, 128, 256, 10, t);
    __syncthreads();
    gcn_agg(hout, nullptr, b3, deginv, row_start, col, val, hd, 256, true, g, t);
}

// ---------------- fully fused co-attention, one block (512 thr) per graph ----------------
__global__ __launch_bounds__(512) void k_coatt(
    const ushort* __restrict__ tWb, const ushort* __restrict__ t2,
    const float* __restrict__ hd2,
    const float* __restrict__ W_c, const float* __restrict__ W_p,
    const float* __restrict__ w_hc, const float* __restrict__ w_hp,
    float* __restrict__ cp)
{
    __shared__ float  sx[48][132];     // hd2 rows (45 used)
    __shared__ float  sWp[32][132];    // W_p
    __shared__ float  sWcx[32][48];    // Wcx
    __shared__ float  sHc[32][49];     // Hc accumulator
    __shared__ ushort sT[128][132];    // t2 / tWb chunk (bf16)
    __shared__ float  sC[128][49];     // C chunk
    __shared__ float  sWpt[32][132];   // W_c temp, then Wpt/Hp chunk
    __shared__ float  sLogit[512];
    __shared__ float  sLc[48];
    __shared__ float  swh[64];         // [0:32) w_hc, [32:64) w_hp
    __shared__ float  sRed[8], sRed2[8];
    __shared__ float  sPc[4][128];

    const int b = blockIdx.x, tid = threadIdx.x;

    // ---- init loads ----
    for (int o = tid; o < 45 * 128; o += 512) sx[o >> 7][o & 127] = hd2[(b * 45 + (o >> 7)) * 128 + (o & 127)];
    for (int o = tid; o < 32 * 128; o += 512) sWp[o >> 7][o & 127] = W_p[o];
    for (int o = tid; o < 32 * 128; o += 512) sWpt[o >> 7][o & 127] = W_c[o];  // temp: W_c
    if (tid < 64) swh[tid] = (tid < 32) ? w_hc[tid] : w_hp[tid - 32];
    for (int o = tid; o < 32 * 49; o += 512) (&sHc[0][0])[o] = 0.f;
    __syncthreads();

    // ---- Wcx[k][s] = sum_m W_c[k][m] * hd2[s][m] ----
    {
        int k = tid >> 4, si = tid & 15;
        float a0 = 0.f, a1 = 0.f, a2 = 0.f;
        for (int m = 0; m < 128; m++) {
            float w = sWpt[k][m];
            a0 += w * sx[si][m]; a1 += w * sx[si + 16][m]; a2 += w * sx[si + 32][m];
        }
        sWcx[k][si] = a0; sWcx[k][si + 16] = a1;
        if (si < 13) sWcx[k][si + 32] = a2;
    }
    __syncthreads();

    const ushort* t2b  = t2  + ((size_t)b * 512) * 128;
    const ushort* tWbb = tWb + ((size_t)b * 512) * 128;

    for (int lc = 0; lc < 4; lc++) {
        // 1. load t2 chunk -> sT
        {
            const ushort* src = t2b + lc * 128 * 128;
#pragma unroll
            for (int i = 0; i < 8; i++) {
                int idx = tid + i * 512;                  // uint2 index
                int row = idx >> 5, c4 = (idx & 31) * 4;
                *(uint2*)&sT[row][c4] = *(const uint2*)(src + row * 128 + c4);
            }
        }
        __syncthreads();
        // 2. Wpt[k][l] = sum_m W_p[k][m] * t2[l][m]   (2k x 4l per thread)
        {
            int kg = tid >> 5, li = tid & 31;
            float acc[8] = {};
            for (int m = 0; m < 128; m++) {
                float w0 = sWp[2 * kg][m], w1 = sWp[2 * kg + 1][m];
#pragma unroll
                for (int u = 0; u < 4; u++) {
                    float tv = bf2f(sT[li + 32 * u][m]);
                    acc[u] += w0 * tv; acc[4 + u] += w1 * tv;
                }
            }
#pragma unroll
            for (int u = 0; u < 4; u++) {
                sWpt[2 * kg][li + 32 * u] = acc[u];
                sWpt[2 * kg + 1][li + 32 * u] = acc[4 + u];
            }
        }
        __syncthreads();
        // 3. load tWb chunk -> sT
        {
            const ushort* src = tWbb + lc * 128 * 128;
#pragma unroll
            for (int i = 0; i < 8; i++) {
                int idx = tid + i * 512;
                int row = idx >> 5, c4 = (idx & 31) * 4;
                *(uint2*)&sT[row][c4] = *(const uint2*)(src + row * 128 + c4);
            }
        }
        __syncthreads();
        // 4. C[l][s] = tanh(sum_m tWb[l][m] * hd2[s][m])   (2l x 6s per thread)
        {
            int lg = tid >> 3, sg = tid & 7;
            float acc[12] = {};
            for (int m = 0; m < 128; m++) {
                float t0 = bf2f(sT[2 * lg][m]), t1 = bf2f(sT[2 * lg + 1][m]);
#pragma unroll
                for (int u = 0; u < 6; u++) {
                    float xv = sx[6 * sg + u][m];
                    acc[u] += t0 * xv; acc[6 + u] += t1 * xv;
                }
            }
#pragma unroll
            for (int u = 0; u < 6; u++) {
                int s = 6 * sg + u;
                if (s < 45) {
                    sC[2 * lg][s] = tanhf(acc[u]);
                    sC[2 * lg + 1][s] = tanhf(acc[6 + u]);
                }
            }
        }
        __syncthreads();
        // 5. Hc partial: sHc[k][s] += sum_l Wpt[k][l] * C[l][s]
        {
            int k = tid >> 4, si = tid & 15;
            float a0 = 0.f, a1 = 0.f, a2 = 0.f;
            for (int l = 0; l < 128; l++) {
                float w = sWpt[k][l];
                a0 += w * sC[l][si]; a1 += w * sC[l][si + 16]; a2 += w * sC[l][si + 32];
            }
            sHc[k][si] += a0; sHc[k][si + 16] += a1;
            if (si < 13) sHc[k][si + 32] += a2;
        }
        // 6. Hp[k][l] = tanh(Wpt[k][l] + sum_s Wcx[k][s]*C[l][s])  (regs)
        float hp[8];
        {
            int kg = tid >> 5, li = tid & 31;
            float acc[8] = {};
            for (int s = 0; s < 45; s++) {
                float w0 = sWcx[2 * kg][s], w1 = sWcx[2 * kg + 1][s];
#pragma unroll
                for (int u = 0; u < 4; u++) {
                    float cv = sC[li + 32 * u][s];
                    acc[u] += w0 * cv; acc[4 + u] += w1 * cv;
                }
            }
#pragma unroll
            for (int u = 0; u < 4; u++) {
                hp[u]     = tanhf(sWpt[2 * kg][li + 32 * u] + acc[u]);
                hp[4 + u] = tanhf(sWpt[2 * kg + 1][li + 32 * u] + acc[4 + u]);
            }
        }
        __syncthreads();
        // 7. store Hp back into sWpt
        {
            int kg = tid >> 5, li = tid & 31;
#pragma unroll
            for (int u = 0; u < 4; u++) {
                sWpt[2 * kg][li + 32 * u] = hp[u];
                sWpt[2 * kg + 1][li + 32 * u] = hp[4 + u];
            }
        }
        __syncthreads();
        // 8. ap logits for this chunk
        if (tid < 128) {
            float a = 0.f;
            for (int k = 0; k < 32; k++) a += swh[32 + k] * sWpt[k][tid];
            sLogit[lc * 128 + tid] = a;
        }
        __syncthreads();
    }

    // ---- Hc finalize ----
    {
        int k = tid >> 4, si = tid & 15;
        sHc[k][si] = tanhf(sWcx[k][si] + sHc[k][si]);
        sHc[k][si + 16] = tanhf(sWcx[k][si + 16] + sHc[k][si + 16]);
        if (si < 13) sHc[k][si + 32] = tanhf(sWcx[k][si + 32] + sHc[k][si + 32]);
    }
    __syncthreads();
    // ---- ac logits ----
    if (tid < 45) {
        float a = 0.f;
        for (int k = 0; k < 32; k++) a += swh[k] * sHc[k][tid];
        sLc[tid] = a;
    }
    __syncthreads();
    // ---- ac softmax (wave 0) ----
    if (tid < 64) {
        float v = (tid < 45) ? sLc[tid] : -1e30f;
        float mx = v;
        for (int off = 32; off; off >>= 1) mx = fmaxf(mx, __shfl_xor(mx, off));
        float e = (tid < 45) ? expf(v - mx) : 0.f;
        float sm = e;
        for (int off = 32; off; off >>= 1) sm += __shfl_xor(sm, off);
        if (tid < 45) sLc[tid] = e / sm;
    }
    __syncthreads();
    // ---- c = sum_s ac[s]*hd2[s][m] ----
    if (tid < 128) {
        float c = 0.f;
        for (int s = 0; s < 45; s++) c += sLc[s] * sx[s][tid];
        cp[b * 256 + tid] = c;
    }
    // ---- ap softmax over 512 ----
    {
        float v = sLogit[tid];
        float mx = v;
        for (int off = 32; off; off >>= 1) mx = fmaxf(mx, __shfl_xor(mx, off));
        if ((tid & 63) == 0) sRed[tid >> 6] = mx;
        __syncthreads();
        mx = sRed[0];
#pragma unroll
        for (int w = 1; w < 8; w++) mx = fmaxf(mx, sRed[w]);
        float e = expf(v - mx);
        float sm = e;
        for (int off = 32; off; off >>= 1) sm += __shfl_xor(sm, off);
        if ((tid & 63) == 0) sRed2[tid >> 6] = sm;
        __syncthreads();
        sm = 0.f;
#pragma unroll
        for (int w = 0; w < 8; w++) sm += sRed2[w];
        sLogit[tid] = e / sm;
    }
    __syncthreads();
    // ---- p = sum_l ap[l]*t2[l][m] (4-way split over l) ----
    {
        int gq = tid >> 7, m = tid & 127;
        float pp = 0.f;
        for (int l = gq * 128; l < gq * 128 + 128; l++)
            pp += sLogit[l] * bf2f(t2b[l * 128 + m]);
        sPc[gq][m] = pp;
    }
    __syncthreads();
    if (tid < 128)
        cp[b * 256 + 128 + tid] = sPc[0][tid] + sPc[1][tid] + sPc[2][tid] + sPc[3][tid];
}

// ---------------- fused head MLP: relu(relu(cp@W1+b1)@W2+b2)@outW + outb ----------------
__global__ __launch_bounds__(256) void k_head(
    const float* __restrict__ cp, const float* __restrict__ W1, const float* __restrict__ b1,
    const float* __restrict__ W2, const float* __restrict__ b2,
    const float* __restrict__ outW, const float* __restrict__ outb, float* __restrict__ out)
{
    int b = blockIdx.x, t = threadIdx.x;
    __shared__ float sin[256];
    __shared__ float s1[1024];
    __shared__ float s2[512];
    __shared__ float r[4];
    sin[t] = cp[b * 256 + t];
    __syncthreads();
#pragma unroll
    for (int j = 0; j < 4; j++) {
        int n = t + j * 256;
        float a = b1[n];
        for (int k = 0; k < 256; k++) a += sin[k] * W1[k * 1024 + n];
        s1[n] = fmaxf(a, 0.f);
    }
    __syncthreads();
#pragma unroll
    for (int j = 0; j < 2; j++) {
        int n = t + j * 256;
        float a = b2[n];
        for (int k = 0; k < 1024; k++) a += s1[k] * W2[k * 512 + n];
        s2[n] = fmaxf(a, 0.f);
    }
    __syncthreads();
    float a = 0.f;
    for (int k = t; k < 512; k += 256) a += s2[k] * outW[k];
    for (int off = 32; off; off >>= 1) a += __shfl_xor(a, off);
    if ((t & 63) == 0) r[t >> 6] = a;
    __syncthreads();
    if (t == 0) out[b] = r[0] + r[1] + r[2] + r[3] + outb[0];
}

extern "C" void kernel_launch(void* const* d_in, const int* in_sizes, int n_in,
                              void* d_out, int out_size, void* d_ws, size_t ws_size,
                              hipStream_t stream) {
    const float* x        = (const float*)d_in[0];
    const int*   ei       = (const int*)d_in[1];
    const int*   tgt      = (const int*)d_in[2];
    const float* proteins = (const float*)d_in[4];
    const float* gW1 = (const float*)d_in[5];  const float* gb1 = (const float*)d_in[6];
    const float* gW2 = (const float*)d_in[7];  const float* gb2 = (const float*)d_in[8];
    const float* gW3 = (const float*)d_in[9];  const float* gb3 = (const float*)d_in[10];
    const float* fc1_W = (const float*)d_in[11]; const float* fc1_b = (const float*)d_in[12];
    const float* fc2_W = (const float*)d_in[13]; const float* fc2_b = (const float*)d_in[14];
    const float* bert1_W = (const float*)d_in[15]; const float* bert1_b = (const float*)d_in[16];
    const float* bert2_W = (const float*)d_in[17]; const float* bert2_b = (const float*)d_in[18];
    const float* W_b = (const float*)d_in[19];
    const float* W_c = (const float*)d_in[20];
    const float* W_p = (const float*)d_in[21];
    const float* w_hc = (const float*)d_in[22];
    const float* w_hp = (const float*)d_in[23];
    const float* cat1_W = (const float*)d_in[24]; const float* cat1_b = (const float*)d_in[25];
    const float* cat2_W = (const float*)d_in[26]; const float* cat2_b = (const float*)d_in[27];
    const float* out_W = (const float*)d_in[28]; const float* out_b = (const float*)d_in[29];

    const int* src = ei;
    const int* dst = ei + NE;

    // ---- workspace layout ----
    char* w = (char*)d_ws;
    auto alloc = [&](size_t bytes) -> void* {
        void* p = (void*)w;
        w += (bytes + 255) & ~(size_t)255;
        return p;
    };
    int*   cnt       = (int*)alloc((size_t)2 * NNODE * 4);  // cnt + cursor adjacent (one memset)
    int*   cursor    = cnt + NNODE;
    int*   row_start = (int*)alloc((NNODE + 1) * 4);
    int*   colv      = (int*)alloc(NE * 4);
    float* valv      = (float*)alloc(NE * 4);
    float* dinv      = (float*)alloc(NNODE * 4);
    float* deginv    = (float*)alloc(NNODE * 4);
    float* hd        = (float*)alloc((size_t)5760 * 256 * 4);   // dense GCN out
    bf16*  fc1o      = (bf16*)alloc((size_t)5760 * 1024 * 2);
    float* hd2       = (float*)alloc((size_t)5760 * 128 * 4);
    bf16*  t1        = (bf16*)alloc((size_t)65536 * 128 * 2);   // aliased by tWb
    bf16*  t2        = (bf16*)alloc((size_t)65536 * 128 * 2);
    float* cp        = (float*)alloc((size_t)NB * 256 * 4);
    ushort* fc1_WT   = (ushort*)alloc((size_t)1024 * 256 * 2);
    ushort* fc2_WT   = (ushort*)alloc((size_t)128 * 1024 * 2);
    ushort* bert1_WT = (ushort*)alloc((size_t)128 * 1280 * 2);
    ushort* bert2_WT = (ushort*)alloc((size_t)128 * 128 * 2);
    ushort* W_bT     = (ushort*)alloc((size_t)128 * 128 * 2);
    bf16*  tWb = t1;   // t1 dead after bert2

    // 1. all weight transposes
    k_transp_all<<<576, 256, 0, stream>>>(fc1_W, fc2_W, bert1_W, bert2_W, W_b,
                                          fc1_WT, fc2_WT, bert1_WT, bert2_WT, W_bT);
    // 2. zero cnt+cursor
    hipMemsetAsync(cnt, 0, (size_t)2 * NNODE * 4, stream);
    // 3-5. CSR build
    k_count<<<(NE + 255) / 256, 256, 0, stream>>>(dst, cnt, NE);
    k_scan<<<1, 1024, 0, stream>>>(cnt, row_start, dinv, deginv, NNODE);
    k_fill<<<(NE + 255) / 256, 256, 0, stream>>>(src, dst, row_start, cursor, colv, valv, dinv, NE);
    // 6. fused GCN stack -> dense hd (incl. zero pads)
    k_gcn<<<NB, 256, 0, stream>>>(x, gW1, gb1, gW2, gb2, gW3, gb3,
                                  deginv, row_start, colv, valv, hd);
    // 7-8. dense graph MLP (MFMA)
    gemm_mfma<float, bf16, 1, false><<<dim3(45, 8), 256, 0, stream>>>(hd, fc1_WT, fc1_b, fc1o, 5760, 1024, 256, nullptr);
    gemm_mfma<ushort, float, 1, false><<<dim3(45, 1), 256, 0, stream>>>((const ushort*)fc1o, fc2_WT, fc2_b, hd2, 5760, 128, 1024, nullptr);
    // 9-11. protein branch (MFMA; gather fused into bert1 A-staging)
    gemm_mfma<float, bf16, 1, true><<<dim3(512, 1), 256, 0, stream>>>(proteins, bert1_WT, bert1_b, t1, 65536, 128, 1280, tgt);
    gemm_mfma<ushort, bf16, 1, false><<<dim3(512, 1), 256, 0, stream>>>((const ushort*)t1, bert2_WT, bert2_b, t2, 65536, 128, 128, nullptr);
    gemm_mfma<ushort, bf16, 0, false><<<dim3(512, 1), 256, 0, stream>>>((const ushort*)t2, W_bT, nullptr, tWb, 65536, 128, 128, nullptr);
    // 12. fused co-attention -> cp
    k_coatt<<<NB, 512, 0, stream>>>((const ushort*)tWb, (const ushort*)t2, hd2,
                                    W_c, W_p, w_hc, w_hp, cp);
    // 13. fused head MLP -> out
    k_head<<<NB, 256, 0, stream>>>(cp, cat1_W, cat1_b, cat2_W, cat2_b, out_W, out_b, (float*)d_out);
}

// Round 4
// 1240.129 us; speedup vs baseline: 1.8626x; 1.0249x over previous
//
#include <hip/hip_runtime.h>
#include <hip/hip_bf16.h>

typedef __hip_bfloat16 bf16;
typedef __bf16 bf16x8 __attribute__((ext_vector_type(8)));
typedef float f32x4 __attribute__((ext_vector_type(4)));

#define NB   128   // graphs
#define NPGX 40    // nodes per graph
#define NNODE 5120 // total nodes
#define NE   20000 // edges
#define LPX  512   // protein seq len
#define MAXNX 45

__device__ __forceinline__ void stv(float* p, float v) { *p = v; }
__device__ __forceinline__ void stv(bf16* p, float v) { *p = __float2bfloat16(v); }
// fp32 -> bf16 bits, round-to-nearest-even
__device__ __forceinline__ ushort f2bf(float f) {
    uint x = __float_as_uint(f);
    return (ushort)((x + 0x7fffu + ((x >> 16) & 1u)) >> 16);
}
__device__ __forceinline__ float bf2f(ushort u) { return __uint_as_float(((uint)u) << 16); }
__device__ __forceinline__ float dot4(f32x4 a, f32x4 b) {
    return a[0]*b[0] + a[1]*b[1] + a[2]*b[2] + a[3]*b[3];
}

// ---------------- MFMA bf16 GEMM: C = act(A[M,K] @ BT[N,K]^T + bias) ----------------
template <typename TA, typename TO, int ACT, bool GATHER>
__global__ __launch_bounds__(256) void gemm_mfma(
    const TA* __restrict__ A, const ushort* __restrict__ BT, const float* __restrict__ bias,
    TO* __restrict__ C, int M, int N, int K, const int* __restrict__ tgt)
{
    __shared__ __align__(16) ushort sA[128][40];   // pad 40: row stride 80B
    __shared__ __align__(16) ushort sB[128][40];
    const int t = threadIdx.x;
    const int lane = t & 63;
    const int wave = t >> 6;
    const int wr = wave >> 1, wc = wave & 1;
    const int m0 = blockIdx.x * 128;
    const int n0 = blockIdx.y * 128;
    const int fr = lane & 15;
    const int kh = lane >> 4;

    f32x4 acc[4][4] = {};

    for (int k0 = 0; k0 < K; k0 += 32) {
        if constexpr (sizeof(TA) == 2) {
            const ushort* Ap = (const ushort*)A;
#pragma unroll
            for (int i = 0; i < 2; i++) {
                int linear = i * 2048 + t * 8;
                int row = linear >> 5, k = linear & 31;
                long gr = m0 + row;
                uint4 v = *(const uint4*)(Ap + gr * (long)K + k0 + k);
                *(uint4*)&sA[row][k] = v;
            }
        } else {
            const float* Ap = (const float*)A;
#pragma unroll
            for (int i = 0; i < 4; i++) {
                int linear = i * 1024 + t * 4;
                int row = linear >> 5, k = linear & 31;
                long gr = m0 + row;
                if (GATHER) { int bb = (int)(gr >> 9); gr = (long)tgt[bb] * LPX + (gr & 511); }
                float4 v = *(const float4*)(Ap + gr * (long)K + k0 + k);
                ushort4 h;
                h.x = f2bf(v.x); h.y = f2bf(v.y); h.z = f2bf(v.z); h.w = f2bf(v.w);
                *(ushort4*)&sA[row][k] = h;
            }
        }
#pragma unroll
        for (int i = 0; i < 2; i++) {
            int linear = i * 2048 + t * 8;
            int row = linear >> 5, k = linear & 31;
            uint4 v = *(const uint4*)(BT + (long)(n0 + row) * K + k0 + k);
            *(uint4*)&sB[row][k] = v;
        }
        __syncthreads();

        bf16x8 a[4], b[4];
#pragma unroll
        for (int mf = 0; mf < 4; mf++)
            a[mf] = *(const bf16x8*)&sA[wr * 64 + mf * 16 + fr][kh * 8];
#pragma unroll
        for (int nf = 0; nf < 4; nf++)
            b[nf] = *(const bf16x8*)&sB[wc * 64 + nf * 16 + fr][kh * 8];
#pragma unroll
        for (int mf = 0; mf < 4; mf++)
#pragma unroll
            for (int nf = 0; nf < 4; nf++)
                acc[mf][nf] = __builtin_amdgcn_mfma_f32_16x16x32_bf16(a[mf], b[nf], acc[mf][nf], 0, 0, 0);
        __syncthreads();
    }

#pragma unroll
    for (int mf = 0; mf < 4; mf++) {
#pragma unroll
        for (int nf = 0; nf < 4; nf++) {
            int coln = n0 + wc * 64 + nf * 16 + fr;
            float bv = bias ? bias[coln] : 0.f;
#pragma unroll
            for (int r = 0; r < 4; r++) {
                int row = m0 + wr * 64 + mf * 16 + kh * 4 + r;
                float v = acc[mf][nf][r] + bv;
                if (ACT == 1) v = fmaxf(v, 0.f);
                else if (ACT == 2) v = tanhf(v);
                stv(&C[(long)row * N + coln], v);
            }
        }
    }
}

// ---------------- 4 weight transposes in ONE dispatch ----------------
__global__ __launch_bounds__(256) void k_transp_all(
    const float* __restrict__ s0, const float* __restrict__ s1, const float* __restrict__ s2,
    const float* __restrict__ s3,
    ushort* __restrict__ d0, ushort* __restrict__ d1, ushort* __restrict__ d2,
    ushort* __restrict__ d3)
{
    __shared__ float s[32][33];
    int bid = blockIdx.x;
    const float* in; ushort* out; int K, N, b;
    if (bid < 256)      { in = s0; out = d0; K = 256;  N = 1024; b = bid; }        // fc1_W  8x32
    else if (bid < 384) { in = s1; out = d1; K = 1024; N = 128;  b = bid - 256; }  // fc2_W  32x4
    else if (bid < 544) { in = s2; out = d2; K = 1280; N = 128;  b = bid - 384; }  // bert1  40x4
    else                { in = s3; out = d3; K = 128;  N = 128;  b = bid - 544; }  // bert2  4x4
    int ktiles = K / 32;
    int kt = (b % ktiles) * 32, nt = (b / ktiles) * 32;
    int t = threadIdx.x;
    int tn = t & 31, tk = t >> 5;
#pragma unroll
    for (int i = 0; i < 4; i++)
        s[tk + i * 8][tn] = in[(long)(kt + tk + i * 8) * N + nt + tn];
    __syncthreads();
#pragma unroll
    for (int i = 0; i < 4; i++)
        out[(long)(nt + tk + i * 8) * K + kt + tn] = f2bf(s[tn][tk + i * 8]);
}

// ---------------- GCN graph preprocessing ----------------
__global__ void k_count(const int* __restrict__ dst, int* __restrict__ cnt, int E) {
    int e = blockIdx.x * 256 + threadIdx.x;
    if (e < E) atomicAdd(&cnt[dst[e]], 1);
}

__global__ void k_scan(const int* __restrict__ cnt, int* __restrict__ row_start,
                       float* __restrict__ dinv, float* __restrict__ deginv, int n) {
    __shared__ int sd[1024];
    __shared__ int scarry;
    int t = threadIdx.x;
    if (t == 0) scarry = 0;
    __syncthreads();
    for (int base = 0; base < n; base += 1024) {
        int i = base + t;
        int v = (i < n) ? cnt[i] : 0;
        sd[t] = v;
        __syncthreads();
        for (int off = 1; off < 1024; off <<= 1) {
            int tmp = (t >= off) ? sd[t - off] : 0;
            __syncthreads();
            sd[t] += tmp;
            __syncthreads();
        }
        int carry = scarry;
        if (i < n) {
            row_start[i] = carry + sd[t] - v;
            float deg = (float)(v + 1);
            dinv[i] = rsqrtf(deg);
            deginv[i] = 1.f / deg;
        }
        __syncthreads();
        if (t == 1023) scarry = carry + sd[1023];
        __syncthreads();
    }
    if (t == 0) row_start[n] = scarry;
}

__global__ void k_fill(const int* __restrict__ src, const int* __restrict__ dst,
                       const int* __restrict__ row_start, int* __restrict__ cursor,
                       int* __restrict__ col, float* __restrict__ val,
                       const float* __restrict__ dinv, int E) {
    int e = blockIdx.x * 256 + threadIdx.x;
    if (e >= E) return;
    int d = dst[e], s = src[e];
    int p = atomicAdd(&cursor[d], 1);
    int idx = row_start[d] + p;
    col[idx] = s;
    val[idx] = dinv[s] * dinv[d];
}

// ---------------- fully fused 3-layer GCN, one block per graph ----------------
__device__ __forceinline__ void gcn_gemm(const float (*hin)[132], float (*hout)[260],
                                         float (*sW)[260], const float* __restrict__ Wg,
                                         int K, int N, int NQ, int t) {
    f32x4 acc[10] = {};   // NQ <= 10
    for (int k0 = 0; k0 < K; k0 += 32) {
        int kmax = min(32, K - k0);
        int kpad = (kmax + 3) & ~3;
        __syncthreads();
        for (int o = t; o < kpad * N; o += 256) {
            int row = o / N, c = o - row * N;
            sW[row][c] = (row < kmax) ? Wg[(k0 + row) * N + c] : 0.f;
        }
        __syncthreads();
        for (int kk = 0; kk < kpad; kk += 4) {
#pragma unroll 10
            for (int j = 0; j < NQ; j++) {
                int q = t + j * 256;
                int i = q / (N / 4), f = (q % (N / 4)) * 4;
                f32x4 hv = *(const f32x4*)&hin[i][k0 + kk];
#pragma unroll
                for (int d = 0; d < 4; d++) {
                    f32x4 wv = *(const f32x4*)&sW[kk + d][f];
                    acc[j][0] = fmaf(hv[d], wv[0], acc[j][0]);
                    acc[j][1] = fmaf(hv[d], wv[1], acc[j][1]);
                    acc[j][2] = fmaf(hv[d], wv[2], acc[j][2]);
                    acc[j][3] = fmaf(hv[d], wv[3], acc[j][3]);
                }
            }
        }
    }
    __syncthreads();
#pragma unroll 10
    for (int j = 0; j < NQ; j++) {
        int q = t + j * 256;
        int i = q / (N / 4), f = (q % (N / 4)) * 4;
        *(f32x4*)&hout[i][f] = acc[j];
    }
}

__device__ __forceinline__ void gcn_agg(const float (*hout)[260], float (*hin)[132],
                                        const float* __restrict__ bias,
                                        const float* __restrict__ deginv,
                                        const int* __restrict__ row_start,
                                        const int* __restrict__ col,
                                        const float* __restrict__ val,
                                        float* __restrict__ hd, int N, bool tohd, int g, int t) {
    int base = g * NPGX;
    for (int o = t; o < 40 * N; o += 256) {
        int i = o / N, f = o - i * N;
        float s = hout[i][f] * deginv[base + i];
        int e0 = row_start[base + i], e1 = row_start[base + i + 1];
        for (int e = e0; e < e1; e++) s += val[e] * hout[col[e] - base][f];
        s += bias[f];
        s = fmaxf(s, 0.f);
        if (tohd) hd[(g * MAXNX + i) * N + f] = s;
        else      hin[i][f] = s;
    }
    if (tohd) for (int o = t; o < 5 * N; o += 256) hd[(g * MAXNX + 40) * N + o] = 0.f;
}

__global__ __launch_bounds__(256) void k_gcn(
    const float* __restrict__ x,
    const float* __restrict__ W1, const float* __restrict__ b1,
    const float* __restrict__ W2, const float* __restrict__ b2,
    const float* __restrict__ W3, const float* __restrict__ b3,
    const float* __restrict__ deginv, const int* __restrict__ row_start,
    const int* __restrict__ col, const float* __restrict__ val,
    float* __restrict__ hd)
{
    int g = blockIdx.x, t = threadIdx.x;
    __shared__ __align__(16) float hin[40][132];
    __shared__ __align__(16) float hout[40][260];
    __shared__ __align__(16) float sW[32][260];
    // preload x rows (40 x 78) and zero pad cols 78..79 (for 4-wide kk unroll)
    for (int o = t; o < 40 * 78; o += 256) hin[o / 78][o % 78] = x[(g * NPGX + o / 78) * 78 + o % 78];
    for (int o = t; o < 80; o += 256) hin[o >> 1][78 + (o & 1)] = 0.f;
    // layer 1: K=78 N=128
    gcn_gemm(hin, hout, sW, W1, 78, 128, 5, t);
    __syncthreads();
    gcn_agg(hout, hin, b1, deginv, row_start, col, val, nullptr, 128, false, g, t);
    __syncthreads();
    // layer 2: K=128 N=128
    gcn_gemm(hin, hout, sW, W2, 128, 128, 5, t);
    __syncthreads();
    gcn_agg(hout, hin, b2, deginv, row_start, col, val, nullptr, 128, false, g, t);
    __syncthreads();
    // layer 3: K=128 N=256 -> dense hd (incl. zero pad rows)
    gcn_gemm(hin, hout, sW, W3, 128, 256, 10, t);
    __syncthreads();
    gcn_agg(hout, nullptr, b3, deginv, row_start, col, val, hd, 256, true, g, t);
}

// ---------------- fused co-attention v2: MFMA C/Wpt + Y-trick ----------------
// Per graph (one 512-thread block):
//   Y[s][k]   = sum_m W_b[k][m] * hd2[s][m]          (fp32 -> bf16; replaces tWb GEMM)
//   Wcx[k][s] = sum_m W_c[k][m] * hd2[s][m]          (fp32)
//   per 128-l chunk:
//     Wpt[k][l] = MFMA( Wp_bf16, t2_chunk )          (fp32 out)
//     C[l][s]   = tanh( MFMA( t2_chunk, Y ) )        (fp32 LDS)
//     Hc[k][s] += sum_l Wpt[k][l]*C[l][s]            (fp32 vec)
//     Hp[k][l]  = tanh(Wpt + sum_s Wcx[k][s]*C[l][s]) (fp32 vec, in-place)
//     ap_logits[l] = sum_k w_hp[k]*Hp[k][l]
//   then softmaxes + c/p outputs.
__global__ __launch_bounds__(512) void k_coatt(
    const ushort* __restrict__ t2, const float* __restrict__ hd2,
    const float* __restrict__ W_b, const float* __restrict__ W_c,
    const float* __restrict__ W_p, const float* __restrict__ w_hc,
    const float* __restrict__ w_hp, float* __restrict__ cp)
{
    __shared__ __align__(16) float  sx[48][132];    // hd2 rows (45 used; 45..47 zeroed)
    __shared__ __align__(16) ushort sY[48][136];    // Y bf16
    __shared__ __align__(16) ushort sWpb[32][136];  // W_p bf16
    __shared__ __align__(16) float  sWcx[32][48];   // Wcx (cols 45..47 = 0)
    __shared__ __align__(16) float  sHc[32][48];    // Hc accumulator
    __shared__ __align__(16) ushort sT[128][136];   // t2 chunk bf16
    __shared__ __align__(16) float  sC[128][52];    // C chunk fp32 (pad 52: 4-way not 16-way)
    __shared__ __align__(16) float  sWpt[32][132];  // Wpt / Hp chunk fp32
    __shared__ float  sLogit[512];
    __shared__ float  sLc[64];
    __shared__ float  swh[64];
    __shared__ float  sRed[8], sRed2[8];
    __shared__ float  sPc[4][128];

    const int b = blockIdx.x, tid = threadIdx.x;
    const int lane = tid & 63, wave = tid >> 6;
    const int fr = lane & 15, kh = lane >> 4;

    // ---- init ----
    for (int o = tid; o < 48 * 32; o += 512) {       // sx: 48 rows x 32 quads
        int r = o >> 5, q = (o & 31) * 4;
        f32x4 v = {0.f, 0.f, 0.f, 0.f};
        if (r < 45) v = *(const f32x4*)&hd2[(b * 45 + r) * 128 + q];
        *(f32x4*)&sx[r][q] = v;
    }
    for (int o = tid; o < 32 * 32; o += 512) {       // W_p -> bf16
        int r = o >> 5, q = (o & 31) * 4;
        f32x4 v = *(const f32x4*)&W_p[r * 128 + q];
        sWpb[r][q] = f2bf(v[0]); sWpb[r][q + 1] = f2bf(v[1]);
        sWpb[r][q + 2] = f2bf(v[2]); sWpb[r][q + 3] = f2bf(v[3]);
    }
    if (tid < 64) swh[tid] = (tid < 32) ? w_hc[tid] : w_hp[tid - 32];
    for (int o = tid; o < 32 * 12; o += 512) {       // zero sHc
        int r = o / 12, q = (o - r * 12) * 4;
        *(f32x4*)&sHc[r][q] = f32x4{0.f, 0.f, 0.f, 0.f};
    }
    __syncthreads();

    // ---- Y[s][k] (thread: 2k x 6s; 512 slots exact) ----
    {
        int kg = tid >> 3, sg = tid & 7;
        float acc[12] = {};
        for (int m = 0; m < 128; m += 4) {
            f32x4 w0 = *(const f32x4*)&W_b[(2 * kg) * 128 + m];
            f32x4 w1 = *(const f32x4*)&W_b[(2 * kg + 1) * 128 + m];
#pragma unroll
            for (int u = 0; u < 6; u++) {
                f32x4 xv = *(const f32x4*)&sx[6 * sg + u][m];
                acc[u] += dot4(w0, xv);
                acc[6 + u] += dot4(w1, xv);
            }
        }
#pragma unroll
        for (int u = 0; u < 6; u++) {
            int s = 6 * sg + u;                      // rows >=45: sx zero -> Y = 0
            sY[s][2 * kg] = f2bf(acc[u]);
            sY[s][2 * kg + 1] = f2bf(acc[6 + u]);
        }
    }
    // ---- Wcx[k][s] (thread: 1k x 6s; 256 threads) ----
    if (tid < 256) {
        int k = tid >> 3, sg = tid & 7;
        float acc[6] = {};
        for (int m = 0; m < 128; m += 4) {
            f32x4 w = *(const f32x4*)&W_c[k * 128 + m];
#pragma unroll
            for (int u = 0; u < 6; u++) {
                f32x4 xv = *(const f32x4*)&sx[6 * sg + u][m];
                acc[u] += dot4(w, xv);
            }
        }
#pragma unroll
        for (int u = 0; u < 6; u++) sWcx[k][6 * sg + u] = acc[u];  // cols>=45 get 0
    }
    __syncthreads();

    const ushort* t2b = t2 + ((size_t)b * 512) * 128;

    for (int lc = 0; lc < 4; lc++) {
        // a. load t2 chunk -> sT
        {
            const ushort* srcp = t2b + lc * 128 * 128;
#pragma unroll
            for (int i = 0; i < 4; i++) {
                int idx = tid + i * 512;             // uint4 units (2048 total)
                int row = idx >> 4, c8 = (idx & 15) * 8;
                *(uint4*)&sT[row][c8] = *(const uint4*)(srcp + row * 128 + c8);
            }
        }
        __syncthreads();
        // c. MFMA: C (3 n-tiles) and Wpt (2 m-tiles); shared sT fragment
        {
            f32x4 cacc[3] = {};
            f32x4 wacc[2] = {};
#pragma unroll
            for (int ks = 0; ks < 4; ks++) {
                bf16x8 af = *(const bf16x8*)&sT[wave * 16 + fr][ks * 32 + kh * 8];
#pragma unroll
                for (int nt = 0; nt < 3; nt++) {
                    bf16x8 bf = *(const bf16x8*)&sY[nt * 16 + fr][ks * 32 + kh * 8];
                    cacc[nt] = __builtin_amdgcn_mfma_f32_16x16x32_bf16(af, bf, cacc[nt], 0, 0, 0);
                }
#pragma unroll
                for (int mt = 0; mt < 2; mt++) {
                    bf16x8 aw = *(const bf16x8*)&sWpb[mt * 16 + fr][ks * 32 + kh * 8];
                    wacc[mt] = __builtin_amdgcn_mfma_f32_16x16x32_bf16(aw, af, wacc[mt], 0, 0, 0);
                }
            }
#pragma unroll
            for (int nt = 0; nt < 3; nt++)
#pragma unroll
                for (int r = 0; r < 4; r++)
                    sC[wave * 16 + kh * 4 + r][nt * 16 + fr] = tanhf(cacc[nt][r]);
#pragma unroll
            for (int mt = 0; mt < 2; mt++)
#pragma unroll
                for (int r = 0; r < 4; r++)
                    sWpt[mt * 16 + kh * 4 + r][wave * 16 + fr] = wacc[mt][r];
        }
        __syncthreads();
        // e1. Hc accumulate (384 thr) + Hp partial sums (512 thr, regs)
        float hpacc[8];
        {
            if (tid < 384) {
                int k = tid / 12, sg = tid - (tid / 12) * 12;
                f32x4 a = {0.f, 0.f, 0.f, 0.f};
                for (int l = 0; l < 128; l++) {
                    float wv = sWpt[k][l];
                    f32x4 cv = *(const f32x4*)&sC[l][sg * 4];
                    a[0] = fmaf(wv, cv[0], a[0]); a[1] = fmaf(wv, cv[1], a[1]);
                    a[2] = fmaf(wv, cv[2], a[2]); a[3] = fmaf(wv, cv[3], a[3]);
                }
                f32x4 h = *(const f32x4*)&sHc[k][sg * 4];
                h[0] += a[0]; h[1] += a[1]; h[2] += a[2]; h[3] += a[3];
                *(f32x4*)&sHc[k][sg * 4] = h;
            }
            int kg = tid >> 5, li = tid & 31;
            float acc[8] = {};
            for (int s4 = 0; s4 < 48; s4 += 4) {
                f32x4 w0 = *(const f32x4*)&sWcx[2 * kg][s4];
                f32x4 w1 = *(const f32x4*)&sWcx[2 * kg + 1][s4];
#pragma unroll
                for (int u = 0; u < 4; u++) {
                    f32x4 cv = *(const f32x4*)&sC[li + 32 * u][s4];
                    acc[u] += dot4(w0, cv);
                    acc[4 + u] += dot4(w1, cv);
                }
            }
#pragma unroll
            for (int u = 0; u < 8; u++) hpacc[u] = acc[u];
        }
        __syncthreads();
        // e2. Hp finalize in-place into sWpt
        {
            int kg = tid >> 5, li = tid & 31;
#pragma unroll
            for (int u = 0; u < 4; u++) {
                sWpt[2 * kg][li + 32 * u] = tanhf(sWpt[2 * kg][li + 32 * u] + hpacc[u]);
                sWpt[2 * kg + 1][li + 32 * u] = tanhf(sWpt[2 * kg + 1][li + 32 * u] + hpacc[4 + u]);
            }
        }
        __syncthreads();
        // f. ap logits for this chunk
        if (tid < 128) {
            float a = 0.f;
            for (int k = 0; k < 32; k++) a += swh[32 + k] * sWpt[k][tid];
            sLogit[lc * 128 + tid] = a;
        }
        __syncthreads();
    }

    // ---- Hc finalize ----
    {
        int k = tid >> 4, si = tid & 15;
        if (tid < 512) {
            sHc[k][si] = tanhf(sWcx[k][si] + sHc[k][si]);
            sHc[k][si + 16] = tanhf(sWcx[k][si + 16] + sHc[k][si + 16]);
            sHc[k][si + 32] = tanhf(sWcx[k][si + 32] + sHc[k][si + 32]);
        }
    }
    __syncthreads();
    // ---- ac logits ----
    if (tid < 45) {
        float a = 0.f;
        for (int k = 0; k < 32; k++) a += swh[k] * sHc[k][tid];
        sLc[tid] = a;
    }
    __syncthreads();
    // ---- ac softmax (wave 0) ----
    if (tid < 64) {
        float v = (tid < 45) ? sLc[tid] : -1e30f;
        float mx = v;
        for (int off = 32; off; off >>= 1) mx = fmaxf(mx, __shfl_xor(mx, off));
        float e = (tid < 45) ? expf(v - mx) : 0.f;
        float sm = e;
        for (int off = 32; off; off >>= 1) sm += __shfl_xor(sm, off);
        if (tid < 45) sLc[tid] = e / sm;
    }
    __syncthreads();
    // ---- c = sum_s ac[s]*hd2[s][m] ----
    if (tid < 128) {
        float c = 0.f;
        for (int s = 0; s < 45; s++) c += sLc[s] * sx[s][tid];
        cp[b * 256 + tid] = c;
    }
    // ---- ap softmax over 512 ----
    {
        float v = sLogit[tid];
        float mx = v;
        for (int off = 32; off; off >>= 1) mx = fmaxf(mx, __shfl_xor(mx, off));
        if ((tid & 63) == 0) sRed[tid >> 6] = mx;
        __syncthreads();
        mx = sRed[0];
#pragma unroll
        for (int w = 1; w < 8; w++) mx = fmaxf(mx, sRed[w]);
        float e = expf(v - mx);
        float sm = e;
        for (int off = 32; off; off >>= 1) sm += __shfl_xor(sm, off);
        if ((tid & 63) == 0) sRed2[tid >> 6] = sm;
        __syncthreads();
        sm = 0.f;
#pragma unroll
        for (int w = 0; w < 8; w++) sm += sRed2[w];
        sLogit[tid] = e / sm;
    }
    __syncthreads();
    // ---- p = sum_l ap[l]*t2[l][m] (4-way split over l) ----
    {
        int gq = tid >> 7, m = tid & 127;
        float pp = 0.f;
        for (int l = gq * 128; l < gq * 128 + 128; l++)
            pp += sLogit[l] * bf2f(t2b[l * 128 + m]);
        sPc[gq][m] = pp;
    }
    __syncthreads();
    if (tid < 128)
        cp[b * 256 + 128 + tid] = sPc[0][tid] + sPc[1][tid] + sPc[2][tid] + sPc[3][tid];
}

// ---------------- fused head MLP ----------------
__global__ __launch_bounds__(256) void k_head(
    const float* __restrict__ cp, const float* __restrict__ W1, const float* __restrict__ b1,
    const float* __restrict__ W2, const float* __restrict__ b2,
    const float* __restrict__ outW, const float* __restrict__ outb, float* __restrict__ out)
{
    int b = blockIdx.x, t = threadIdx.x;
    __shared__ float sin[256];
    __shared__ float s1[1024];
    __shared__ float s2[512];
    __shared__ float r[4];
    sin[t] = cp[b * 256 + t];
    __syncthreads();
#pragma unroll
    for (int j = 0; j < 4; j++) {
        int n = t + j * 256;
        float a = b1[n];
        for (int k = 0; k < 256; k++) a += sin[k] * W1[k * 1024 + n];
        s1[n] = fmaxf(a, 0.f);
    }
    __syncthreads();
#pragma unroll
    for (int j = 0; j < 2; j++) {
        int n = t + j * 256;
        float a = b2[n];
        for (int k = 0; k < 1024; k++) a += s1[k] * W2[k * 512 + n];
        s2[n] = fmaxf(a, 0.f);
    }
    __syncthreads();
    float a = 0.f;
    for (int k = t; k < 512; k += 256) a += s2[k] * outW[k];
    for (int off = 32; off; off >>= 1) a += __shfl_xor(a, off);
    if ((t & 63) == 0) r[t >> 6] = a;
    __syncthreads();
    if (t == 0) out[b] = r[0] + r[1] + r[2] + r[3] + outb[0];
}

extern "C" void kernel_launch(void* const* d_in, const int* in_sizes, int n_in,
                              void* d_out, int out_size, void* d_ws, size_t ws_size,
                              hipStream_t stream) {
    const float* x        = (const float*)d_in[0];
    const int*   ei       = (const int*)d_in[1];
    const int*   tgt      = (const int*)d_in[2];
    const float* proteins = (const float*)d_in[4];
    const float* gW1 = (const float*)d_in[5];  const float* gb1 = (const float*)d_in[6];
    const float* gW2 = (const float*)d_in[7];  const float* gb2 = (const float*)d_in[8];
    const float* gW3 = (const float*)d_in[9];  const float* gb3 = (const float*)d_in[10];
    const float* fc1_W = (const float*)d_in[11]; const float* fc1_b = (const float*)d_in[12];
    const float* fc2_W = (const float*)d_in[13]; const float* fc2_b = (const float*)d_in[14];
    const float* bert1_W = (const float*)d_in[15]; const float* bert1_b = (const float*)d_in[16];
    const float* bert2_W = (const float*)d_in[17]; const float* bert2_b = (const float*)d_in[18];
    const float* W_b = (const float*)d_in[19];
    const float* W_c = (const float*)d_in[20];
    const float* W_p = (const float*)d_in[21];
    const float* w_hc = (const float*)d_in[22];
    const float* w_hp = (const float*)d_in[23];
    const float* cat1_W = (const float*)d_in[24]; const float* cat1_b = (const float*)d_in[25];
    const float* cat2_W = (const float*)d_in[26]; const float* cat2_b = (const float*)d_in[27];
    const float* out_W = (const float*)d_in[28]; const float* out_b = (const float*)d_in[29];

    const int* src = ei;
    const int* dst = ei + NE;

    // ---- workspace layout ----
    char* w = (char*)d_ws;
    auto alloc = [&](size_t bytes) -> void* {
        void* p = (void*)w;
        w += (bytes + 255) & ~(size_t)255;
        return p;
    };
    int*   cnt       = (int*)alloc((size_t)2 * NNODE * 4);  // cnt + cursor (one memset)
    int*   cursor    = cnt + NNODE;
    int*   row_start = (int*)alloc((NNODE + 1) * 4);
    int*   colv      = (int*)alloc(NE * 4);
    float* valv      = (float*)alloc(NE * 4);
    float* dinv      = (float*)alloc(NNODE * 4);
    float* deginv    = (float*)alloc(NNODE * 4);
    float* hd        = (float*)alloc((size_t)5760 * 256 * 4);
    bf16*  fc1o      = (bf16*)alloc((size_t)5760 * 1024 * 2);
    float* hd2       = (float*)alloc((size_t)5760 * 128 * 4);
    bf16*  t1        = (bf16*)alloc((size_t)65536 * 128 * 2);
    bf16*  t2        = (bf16*)alloc((size_t)65536 * 128 * 2);
    float* cp        = (float*)alloc((size_t)NB * 256 * 4);
    ushort* fc1_WT   = (ushort*)alloc((size_t)1024 * 256 * 2);
    ushort* fc2_WT   = (ushort*)alloc((size_t)128 * 1024 * 2);
    ushort* bert1_WT = (ushort*)alloc((size_t)128 * 1280 * 2);
    ushort* bert2_WT = (ushort*)alloc((size_t)128 * 128 * 2);

    // 1. weight transposes (4 matrices)
    k_transp_all<<<560, 256, 0, stream>>>(fc1_W, fc2_W, bert1_W, bert2_W,
                                          fc1_WT, fc2_WT, bert1_WT, bert2_WT);
    // 2. zero cnt+cursor
    hipMemsetAsync(cnt, 0, (size_t)2 * NNODE * 4, stream);
    // 3-5. CSR build
    k_count<<<(NE + 255) / 256, 256, 0, stream>>>(dst, cnt, NE);
    k_scan<<<1, 1024, 0, stream>>>(cnt, row_start, dinv, deginv, NNODE);
    k_fill<<<(NE + 255) / 256, 256, 0, stream>>>(src, dst, row_start, cursor, colv, valv, dinv, NE);
    // 6. fused GCN stack -> dense hd
    k_gcn<<<NB, 256, 0, stream>>>(x, gW1, gb1, gW2, gb2, gW3, gb3,
                                  deginv, row_start, colv, valv, hd);
    // 7-8. dense graph MLP (MFMA)
    gemm_mfma<float, bf16, 1, false><<<dim3(45, 8), 256, 0, stream>>>(hd, fc1_WT, fc1_b, fc1o, 5760, 1024, 256, nullptr);
    gemm_mfma<ushort, float, 1, false><<<dim3(45, 1), 256, 0, stream>>>((const ushort*)fc1o, fc2_WT, fc2_b, hd2, 5760, 128, 1024, nullptr);
    // 9-10. protein branch (MFMA; gather fused into bert1 A-staging)
    gemm_mfma<float, bf16, 1, true><<<dim3(512, 1), 256, 0, stream>>>(proteins, bert1_WT, bert1_b, t1, 65536, 128, 1280, tgt);
    gemm_mfma<ushort, bf16, 1, false><<<dim3(512, 1), 256, 0, stream>>>((const ushort*)t1, bert2_WT, bert2_b, t2, 65536, 128, 128, nullptr);
    // 11. fused co-attention (tWb GEMM eliminated via Y-trick) -> cp
    k_coatt<<<NB, 512, 0, stream>>>((const ushort*)t2, hd2, W_b, W_c, W_p, w_hc, w_hp, cp);
    // 12. fused head MLP -> out
    k_head<<<NB, 256, 0, stream>>>(cp, cat1_W, cat1_b, cat2_W, cat2_b, out_W, out_b, (float*)d_out);
}

// Round 5
// 1164.827 us; speedup vs baseline: 1.9830x; 1.0646x over previous
//
#include <hip/hip_runtime.h>
#include <hip/hip_bf16.h>

typedef __hip_bfloat16 bf16;
typedef __bf16 bf16x8 __attribute__((ext_vector_type(8)));
typedef float f32x4 __attribute__((ext_vector_type(4)));

#define NB   128   // graphs
#define NPGX 40    // nodes per graph
#define NNODE 5120 // total nodes
#define NE   20000 // edges
#define LPX  512   // protein seq len
#define MAXNX 45
#define EMAX 512   // per-graph edge cap (mean 156, 28 sigma headroom)

__device__ __forceinline__ void stv(float* p, float v) { *p = v; }
__device__ __forceinline__ void stv(bf16* p, float v) { *p = __float2bfloat16(v); }
// fp32 -> bf16 bits, round-to-nearest-even
__device__ __forceinline__ ushort f2bf(float f) {
    uint x = __float_as_uint(f);
    return (ushort)((x + 0x7fffu + ((x >> 16) & 1u)) >> 16);
}
__device__ __forceinline__ float bf2f(ushort u) { return __uint_as_float(((uint)u) << 16); }
__device__ __forceinline__ float dot4(f32x4 a, f32x4 b) {
    return a[0]*b[0] + a[1]*b[1] + a[2]*b[2] + a[3]*b[3];
}

// ---------------- MFMA bf16 GEMM 128x128: C = act(A[M,K] @ BT[N,K]^T + bias) ----------------
template <typename TA, typename TO, int ACT, bool GATHER>
__global__ __launch_bounds__(256) void gemm_mfma(
    const TA* __restrict__ A, const ushort* __restrict__ BT, const float* __restrict__ bias,
    TO* __restrict__ C, int M, int N, int K, const int* __restrict__ tgt)
{
    __shared__ __align__(16) ushort sA[128][40];
    __shared__ __align__(16) ushort sB[128][40];
    const int t = threadIdx.x;
    const int lane = t & 63;
    const int wave = t >> 6;
    const int wr = wave >> 1, wc = wave & 1;
    const int m0 = blockIdx.x * 128;
    const int n0 = blockIdx.y * 128;
    const int fr = lane & 15;
    const int kh = lane >> 4;

    f32x4 acc[4][4] = {};

    for (int k0 = 0; k0 < K; k0 += 32) {
        if constexpr (sizeof(TA) == 2) {
            const ushort* Ap = (const ushort*)A;
#pragma unroll
            for (int i = 0; i < 2; i++) {
                int linear = i * 2048 + t * 8;
                int row = linear >> 5, k = linear & 31;
                long gr = m0 + row;
                uint4 v = *(const uint4*)(Ap + gr * (long)K + k0 + k);
                *(uint4*)&sA[row][k] = v;
            }
        } else {
            const float* Ap = (const float*)A;
#pragma unroll
            for (int i = 0; i < 4; i++) {
                int linear = i * 1024 + t * 4;
                int row = linear >> 5, k = linear & 31;
                long gr = m0 + row;
                if (GATHER) { int bb = (int)(gr >> 9); gr = (long)tgt[bb] * LPX + (gr & 511); }
                float4 v = *(const float4*)(Ap + gr * (long)K + k0 + k);
                ushort4 h;
                h.x = f2bf(v.x); h.y = f2bf(v.y); h.z = f2bf(v.z); h.w = f2bf(v.w);
                *(ushort4*)&sA[row][k] = h;
            }
        }
#pragma unroll
        for (int i = 0; i < 2; i++) {
            int linear = i * 2048 + t * 8;
            int row = linear >> 5, k = linear & 31;
            uint4 v = *(const uint4*)(BT + (long)(n0 + row) * K + k0 + k);
            *(uint4*)&sB[row][k] = v;
        }
        __syncthreads();

        bf16x8 a[4], b[4];
#pragma unroll
        for (int mf = 0; mf < 4; mf++)
            a[mf] = *(const bf16x8*)&sA[wr * 64 + mf * 16 + fr][kh * 8];
#pragma unroll
        for (int nf = 0; nf < 4; nf++)
            b[nf] = *(const bf16x8*)&sB[wc * 64 + nf * 16 + fr][kh * 8];
#pragma unroll
        for (int mf = 0; mf < 4; mf++)
#pragma unroll
            for (int nf = 0; nf < 4; nf++)
                acc[mf][nf] = __builtin_amdgcn_mfma_f32_16x16x32_bf16(a[mf], b[nf], acc[mf][nf], 0, 0, 0);
        __syncthreads();
    }

#pragma unroll
    for (int mf = 0; mf < 4; mf++) {
#pragma unroll
        for (int nf = 0; nf < 4; nf++) {
            int coln = n0 + wc * 64 + nf * 16 + fr;
            float bv = bias ? bias[coln] : 0.f;
#pragma unroll
            for (int r = 0; r < 4; r++) {
                int row = m0 + wr * 64 + mf * 16 + kh * 4 + r;
                float v = acc[mf][nf][r] + bv;
                if (ACT == 1) v = fmaxf(v, 0.f);
                else if (ACT == 2) v = tanhf(v);
                stv(&C[(long)row * N + coln], v);
            }
        }
    }
}

// ---------------- MFMA bf16 GEMM 64x64 tile (wider grids for skinny GEMMs) ----------------
// A bf16 [M,K], BT bf16 [N,K], C fp32, ACT=relu. M%64==0, N%64==0, K%32==0.
__global__ __launch_bounds__(256) void gemm_mfma64(
    const ushort* __restrict__ A, const ushort* __restrict__ BT, const float* __restrict__ bias,
    float* __restrict__ C, int M, int N, int K)
{
    __shared__ __align__(16) ushort sA[64][40];
    __shared__ __align__(16) ushort sB[64][40];
    const int t = threadIdx.x;
    const int lane = t & 63;
    const int wave = t >> 6;
    const int wr = wave >> 1, wc = wave & 1;     // 2x2 waves, each 32x32
    const int m0 = blockIdx.x * 64;
    const int n0 = blockIdx.y * 64;
    const int fr = lane & 15;
    const int kh = lane >> 4;

    f32x4 acc[2][2] = {};

    for (int k0 = 0; k0 < K; k0 += 32) {
        {
            int linear = t * 8;                   // 2048 = 64x32
            int row = linear >> 5, k = linear & 31;
            *(uint4*)&sA[row][k] = *(const uint4*)(A + (long)(m0 + row) * K + k0 + k);
            *(uint4*)&sB[row][k] = *(const uint4*)(BT + (long)(n0 + row) * K + k0 + k);
        }
        __syncthreads();
        bf16x8 a[2], b[2];
#pragma unroll
        for (int mf = 0; mf < 2; mf++)
            a[mf] = *(const bf16x8*)&sA[wr * 32 + mf * 16 + fr][kh * 8];
#pragma unroll
        for (int nf = 0; nf < 2; nf++)
            b[nf] = *(const bf16x8*)&sB[wc * 32 + nf * 16 + fr][kh * 8];
#pragma unroll
        for (int mf = 0; mf < 2; mf++)
#pragma unroll
            for (int nf = 0; nf < 2; nf++)
                acc[mf][nf] = __builtin_amdgcn_mfma_f32_16x16x32_bf16(a[mf], b[nf], acc[mf][nf], 0, 0, 0);
        __syncthreads();
    }

#pragma unroll
    for (int mf = 0; mf < 2; mf++) {
#pragma unroll
        for (int nf = 0; nf < 2; nf++) {
            int coln = n0 + wc * 32 + nf * 16 + fr;
            float bv = bias[coln];
#pragma unroll
            for (int r = 0; r < 4; r++) {
                int row = m0 + wr * 32 + mf * 16 + kh * 4 + r;
                C[(long)row * N + coln] = fmaxf(acc[mf][nf][r] + bv, 0.f);
            }
        }
    }
}

// ---------------- k_prep: fused {weight transposes} + {per-graph CSR + 3-layer GCN} ----------------
__device__ __forceinline__ void gcn_gemm(const float (*hin)[132], float (*hout)[260],
                                         float (*sW)[260], const float* __restrict__ Wg,
                                         int K, int N, int NQ, int t) {
    f32x4 acc[10] = {};   // NQ <= 10
    for (int k0 = 0; k0 < K; k0 += 32) {
        int kmax = min(32, K - k0);
        int kpad = (kmax + 3) & ~3;
        __syncthreads();
        for (int o = t; o < kpad * N; o += 256) {
            int row = o / N, c = o - row * N;
            sW[row][c] = (row < kmax) ? Wg[(k0 + row) * N + c] : 0.f;
        }
        __syncthreads();
        for (int kk = 0; kk < kpad; kk += 4) {
#pragma unroll 10
            for (int j = 0; j < NQ; j++) {
                int q = t + j * 256;
                int i = q / (N / 4), f = (q % (N / 4)) * 4;
                f32x4 hv = *(const f32x4*)&hin[i][k0 + kk];
#pragma unroll
                for (int d = 0; d < 4; d++) {
                    f32x4 wv = *(const f32x4*)&sW[kk + d][f];
                    acc[j][0] = fmaf(hv[d], wv[0], acc[j][0]);
                    acc[j][1] = fmaf(hv[d], wv[1], acc[j][1]);
                    acc[j][2] = fmaf(hv[d], wv[2], acc[j][2]);
                    acc[j][3] = fmaf(hv[d], wv[3], acc[j][3]);
                }
            }
        }
    }
    __syncthreads();
#pragma unroll 10
    for (int j = 0; j < NQ; j++) {
        int q = t + j * 256;
        int i = q / (N / 4), f = (q % (N / 4)) * 4;
        *(f32x4*)&hout[i][f] = acc[j];
    }
}

__device__ __forceinline__ void gcn_agg(const float (*hout)[260], float (*hin)[132],
                                        const float* __restrict__ bias,
                                        const float* __restrict__ dgi,
                                        const int* __restrict__ rs,
                                        const int* __restrict__ colv,
                                        const float* __restrict__ valv,
                                        float* __restrict__ hd, int N, bool tohd, int g, int t) {
    for (int o = t; o < 40 * N; o += 256) {
        int i = o / N, f = o - i * N;
        float s = hout[i][f] * dgi[i];
        int e0 = rs[i], e1 = rs[i + 1];
        for (int e = e0; e < e1; e++) s += valv[e] * hout[colv[e]][f];
        s += bias[f];
        s = fmaxf(s, 0.f);
        if (tohd) hd[(g * MAXNX + i) * N + f] = s;
        else      hin[i][f] = s;
    }
    if (tohd) for (int o = t; o < 5 * N; o += 256) hd[(g * MAXNX + 40) * N + o] = 0.f;
}

__global__ __launch_bounds__(256) void k_prep(
    const float* __restrict__ x, const int* __restrict__ ei,
    const float* __restrict__ W1, const float* __restrict__ b1,
    const float* __restrict__ W2, const float* __restrict__ b2,
    const float* __restrict__ W3, const float* __restrict__ b3,
    float* __restrict__ hd,
    const float* __restrict__ ws0, const float* __restrict__ ws1,
    const float* __restrict__ ws2, const float* __restrict__ ws3,
    ushort* __restrict__ wd0, ushort* __restrict__ wd1,
    ushort* __restrict__ wd2, ushort* __restrict__ wd3)
{
    __shared__ __align__(16) float hin[40][132];
    __shared__ __align__(16) float hout[40][260];
    __shared__ __align__(16) float sW[32][260];
    __shared__ int   s_cnt[40], s_cur[40], s_rs[41];
    __shared__ int   s_col[EMAX];
    __shared__ float s_val[EMAX];
    __shared__ float s_dinv[40], s_dgi[40];

    const int t = threadIdx.x;

    if (blockIdx.x >= NB) {
        // ---------- transpose part: out[n][k] = bf16(in[k][n]) ----------
        float (*ts)[33] = reinterpret_cast<float(*)[33]>(&hin[0][0]);
        int bid = blockIdx.x - NB;
        const float* in; ushort* out; int K, N, b;
        if (bid < 256)      { in = ws0; out = wd0; K = 256;  N = 1024; b = bid; }        // fc1_W
        else if (bid < 384) { in = ws1; out = wd1; K = 1024; N = 128;  b = bid - 256; }  // fc2_W
        else if (bid < 544) { in = ws2; out = wd2; K = 1280; N = 128;  b = bid - 384; }  // bert1
        else                { in = ws3; out = wd3; K = 128;  N = 128;  b = bid - 544; }  // bert2
        int ktiles = K / 32;
        int kt = (b % ktiles) * 32, nt = (b / ktiles) * 32;
        int tn = t & 31, tk = t >> 5;
#pragma unroll
        for (int i = 0; i < 4; i++)
            ts[tk + i * 8][tn] = in[(long)(kt + tk + i * 8) * N + nt + tn];
        __syncthreads();
#pragma unroll
        for (int i = 0; i < 4; i++)
            out[(long)(nt + tk + i * 8) * K + kt + tn] = f2bf(ts[tn][tk + i * 8]);
        return;
    }

    // ---------- GCN part: one block per graph ----------
    const int g = blockIdx.x;
    const int base = g * NPGX;
    const int* srcp = ei;
    const int* dstp = ei + NE;

    // local CSR build (edges are intra-graph by construction)
    for (int o = t; o < 40; o += 256) { s_cnt[o] = 0; s_cur[o] = 0; }
    // preload x rows (40x78), zero pad cols 78..79
    for (int o = t; o < 40 * 78; o += 256) hin[o / 78][o % 78] = x[base * 78 + o];
    for (int o = t; o < 80; o += 256) hin[o >> 1][78 + (o & 1)] = 0.f;
    __syncthreads();
    for (int e = t; e < NE; e += 256) {
        int dl = dstp[e] - base;
        if ((unsigned)dl < 40u) atomicAdd(&s_cnt[dl], 1);
    }
    __syncthreads();
    if (t == 0) {
        int acc = 0;
        for (int i = 0; i < 40; i++) { s_rs[i] = acc; acc += s_cnt[i]; }
        s_rs[40] = acc;
    }
    if (t < 40) {
        float deg = (float)(s_cnt[t] + 1);
        s_dinv[t] = rsqrtf(deg);
        s_dgi[t] = 1.f / deg;
    }
    __syncthreads();
    for (int e = t; e < NE; e += 256) {
        int dl = dstp[e] - base;
        if ((unsigned)dl < 40u) {
            int sl = srcp[e] - base;
            int p = atomicAdd(&s_cur[dl], 1);
            int idx = s_rs[dl] + p;
            if (idx < EMAX) { s_col[idx] = sl; s_val[idx] = s_dinv[sl] * s_dinv[dl]; }
        }
    }
    __syncthreads();

    // layer 1: K=78 N=128
    gcn_gemm(hin, hout, sW, W1, 78, 128, 5, t);
    __syncthreads();
    gcn_agg(hout, hin, b1, s_dgi, s_rs, s_col, s_val, nullptr, 128, false, g, t);
    __syncthreads();
    // layer 2: K=128 N=128
    gcn_gemm(hin, hout, sW, W2, 128, 128, 5, t);
    __syncthreads();
    gcn_agg(hout, hin, b2, s_dgi, s_rs, s_col, s_val, nullptr, 128, false, g, t);
    __syncthreads();
    // layer 3: K=128 N=256 -> dense hd (incl. zero pad rows)
    gcn_gemm(hin, hout, sW, W3, 128, 256, 10, t);
    __syncthreads();
    gcn_agg(hout, nullptr, b3, s_dgi, s_rs, s_col, s_val, hd, 256, true, g, t);
}

// ---------------- fused co-attention + head MLP, one block (512 thr) per graph ----------------
__global__ __launch_bounds__(512) void k_coatt_head(
    const ushort* __restrict__ t2, const float* __restrict__ hd2,
    const float* __restrict__ W_b, const float* __restrict__ W_c,
    const float* __restrict__ W_p, const float* __restrict__ w_hc,
    const float* __restrict__ w_hp,
    const float* __restrict__ cat1_W, const float* __restrict__ cat1_b,
    const float* __restrict__ cat2_W, const float* __restrict__ cat2_b,
    const float* __restrict__ outW, const float* __restrict__ outb,
    float* __restrict__ out)
{
    __shared__ __align__(16) float  sx[48][132];
    __shared__ __align__(16) ushort sY[48][136];
    __shared__ __align__(16) ushort sWpb[32][136];
    __shared__ __align__(16) float  sWcx[32][48];
    __shared__ __align__(16) float  sHc[32][48];
    __shared__ __align__(16) ushort sT[128][136];   // t2 chunk; later head scratch
    __shared__ __align__(16) float  sC[128][52];
    __shared__ __align__(16) float  sWpt[32][132];
    __shared__ float  sLogit[512];
    __shared__ float  sLc[64];
    __shared__ float  swh[64];
    __shared__ float  sRed[8], sRed2[8];
    __shared__ float  sPc[4][128];
    __shared__ float  sCin[256];

    const int b = blockIdx.x, tid = threadIdx.x;
    const int lane = tid & 63, wave = tid >> 6;
    const int fr = lane & 15, kh = lane >> 4;

    // ---- init ----
    for (int o = tid; o < 48 * 32; o += 512) {
        int r = o >> 5, q = (o & 31) * 4;
        f32x4 v = {0.f, 0.f, 0.f, 0.f};
        if (r < 45) v = *(const f32x4*)&hd2[(b * 45 + r) * 128 + q];
        *(f32x4*)&sx[r][q] = v;
    }
    for (int o = tid; o < 32 * 32; o += 512) {
        int r = o >> 5, q = (o & 31) * 4;
        f32x4 v = *(const f32x4*)&W_p[r * 128 + q];
        sWpb[r][q] = f2bf(v[0]); sWpb[r][q + 1] = f2bf(v[1]);
        sWpb[r][q + 2] = f2bf(v[2]); sWpb[r][q + 3] = f2bf(v[3]);
    }
    if (tid < 64) swh[tid] = (tid < 32) ? w_hc[tid] : w_hp[tid - 32];
    for (int o = tid; o < 32 * 12; o += 512) {
        int r = o / 12, q = (o - r * 12) * 4;
        *(f32x4*)&sHc[r][q] = f32x4{0.f, 0.f, 0.f, 0.f};
    }
    __syncthreads();

    // ---- Y[s][k] = sum_m W_b[k][m]*hd2[s][m]  (2k x 6s per thread) ----
    {
        int kg = tid >> 3, sg = tid & 7;
        float acc[12] = {};
        for (int m = 0; m < 128; m += 4) {
            f32x4 w0 = *(const f32x4*)&W_b[(2 * kg) * 128 + m];
            f32x4 w1 = *(const f32x4*)&W_b[(2 * kg + 1) * 128 + m];
#pragma unroll
            for (int u = 0; u < 6; u++) {
                f32x4 xv = *(const f32x4*)&sx[6 * sg + u][m];
                acc[u] += dot4(w0, xv);
                acc[6 + u] += dot4(w1, xv);
            }
        }
#pragma unroll
        for (int u = 0; u < 6; u++) {
            int s = 6 * sg + u;
            sY[s][2 * kg] = f2bf(acc[u]);
            sY[s][2 * kg + 1] = f2bf(acc[6 + u]);
        }
    }
    // ---- Wcx[k][s] ----
    if (tid < 256) {
        int k = tid >> 3, sg = tid & 7;
        float acc[6] = {};
        for (int m = 0; m < 128; m += 4) {
            f32x4 w = *(const f32x4*)&W_c[k * 128 + m];
#pragma unroll
            for (int u = 0; u < 6; u++) {
                f32x4 xv = *(const f32x4*)&sx[6 * sg + u][m];
                acc[u] += dot4(w, xv);
            }
        }
#pragma unroll
        for (int u = 0; u < 6; u++) sWcx[k][6 * sg + u] = acc[u];
    }
    __syncthreads();

    const ushort* t2b = t2 + ((size_t)b * 512) * 128;

    for (int lc = 0; lc < 4; lc++) {
        // a. load t2 chunk
        {
            const ushort* srcp = t2b + lc * 128 * 128;
#pragma unroll
            for (int i = 0; i < 4; i++) {
                int idx = tid + i * 512;
                int row = idx >> 4, c8 = (idx & 15) * 8;
                *(uint4*)&sT[row][c8] = *(const uint4*)(srcp + row * 128 + c8);
            }
        }
        __syncthreads();
        // c. MFMA: C (3 n-tiles) + Wpt (2 m-tiles)
        {
            f32x4 cacc[3] = {};
            f32x4 wacc[2] = {};
#pragma unroll
            for (int ks = 0; ks < 4; ks++) {
                bf16x8 af = *(const bf16x8*)&sT[wave * 16 + fr][ks * 32 + kh * 8];
#pragma unroll
                for (int nt = 0; nt < 3; nt++) {
                    bf16x8 bf = *(const bf16x8*)&sY[nt * 16 + fr][ks * 32 + kh * 8];
                    cacc[nt] = __builtin_amdgcn_mfma_f32_16x16x32_bf16(af, bf, cacc[nt], 0, 0, 0);
                }
#pragma unroll
                for (int mt = 0; mt < 2; mt++) {
                    bf16x8 aw = *(const bf16x8*)&sWpb[mt * 16 + fr][ks * 32 + kh * 8];
                    wacc[mt] = __builtin_amdgcn_mfma_f32_16x16x32_bf16(aw, af, wacc[mt], 0, 0, 0);
                }
            }
#pragma unroll
            for (int nt = 0; nt < 3; nt++)
#pragma unroll
                for (int r = 0; r < 4; r++)
                    sC[wave * 16 + kh * 4 + r][nt * 16 + fr] = tanhf(cacc[nt][r]);
#pragma unroll
            for (int mt = 0; mt < 2; mt++)
#pragma unroll
                for (int r = 0; r < 4; r++)
                    sWpt[mt * 16 + kh * 4 + r][wave * 16 + fr] = wacc[mt][r];
        }
        __syncthreads();
        // e1. Hc accumulate (384 thr) + Hp partials (all threads)
        float hpacc[8];
        {
            if (tid < 384) {
                int k = tid / 12, sg = tid - (tid / 12) * 12;
                f32x4 a = {0.f, 0.f, 0.f, 0.f};
                for (int l = 0; l < 128; l++) {
                    float wv = sWpt[k][l];
                    f32x4 cv = *(const f32x4*)&sC[l][sg * 4];
                    a[0] = fmaf(wv, cv[0], a[0]); a[1] = fmaf(wv, cv[1], a[1]);
                    a[2] = fmaf(wv, cv[2], a[2]); a[3] = fmaf(wv, cv[3], a[3]);
                }
                f32x4 h = *(const f32x4*)&sHc[k][sg * 4];
                h[0] += a[0]; h[1] += a[1]; h[2] += a[2]; h[3] += a[3];
                *(f32x4*)&sHc[k][sg * 4] = h;
            }
            int kg = tid >> 5, li = tid & 31;
            float acc[8] = {};
            for (int s4 = 0; s4 < 48; s4 += 4) {
                f32x4 w0 = *(const f32x4*)&sWcx[2 * kg][s4];
                f32x4 w1 = *(const f32x4*)&sWcx[2 * kg + 1][s4];
#pragma unroll
                for (int u = 0; u < 4; u++) {
                    f32x4 cv = *(const f32x4*)&sC[li + 32 * u][s4];
                    acc[u] += dot4(w0, cv);
                    acc[4 + u] += dot4(w1, cv);
                }
            }
#pragma unroll
            for (int u = 0; u < 8; u++) hpacc[u] = acc[u];
        }
        __syncthreads();
        // e2. Hp in-place
        {
            int kg = tid >> 5, li = tid & 31;
#pragma unroll
            for (int u = 0; u < 4; u++) {
                sWpt[2 * kg][li + 32 * u] = tanhf(sWpt[2 * kg][li + 32 * u] + hpacc[u]);
                sWpt[2 * kg + 1][li + 32 * u] = tanhf(sWpt[2 * kg + 1][li + 32 * u] + hpacc[4 + u]);
            }
        }
        __syncthreads();
        // f. ap logits
        if (tid < 128) {
            float a = 0.f;
            for (int k = 0; k < 32; k++) a += swh[32 + k] * sWpt[k][tid];
            sLogit[lc * 128 + tid] = a;
        }
        __syncthreads();
    }

    // ---- Hc finalize ----
    {
        int k = tid >> 4, si = tid & 15;
        sHc[k][si] = tanhf(sWcx[k][si] + sHc[k][si]);
        sHc[k][si + 16] = tanhf(sWcx[k][si + 16] + sHc[k][si + 16]);
        sHc[k][si + 32] = tanhf(sWcx[k][si + 32] + sHc[k][si + 32]);
    }
    __syncthreads();
    // ---- ac logits ----
    if (tid < 45) {
        float a = 0.f;
        for (int k = 0; k < 32; k++) a += swh[k] * sHc[k][tid];
        sLc[tid] = a;
    }
    __syncthreads();
    // ---- ac softmax (wave 0) ----
    if (tid < 64) {
        float v = (tid < 45) ? sLc[tid] : -1e30f;
        float mx = v;
        for (int off = 32; off; off >>= 1) mx = fmaxf(mx, __shfl_xor(mx, off));
        float e = (tid < 45) ? expf(v - mx) : 0.f;
        float sm = e;
        for (int off = 32; off; off >>= 1) sm += __shfl_xor(sm, off);
        if (tid < 45) sLc[tid] = e / sm;
    }
    __syncthreads();
    // ---- c ----
    if (tid < 128) {
        float c = 0.f;
        for (int s = 0; s < 45; s++) c += sLc[s] * sx[s][tid];
        sCin[tid] = c;
    }
    // ---- ap softmax over 512 ----
    {
        float v = sLogit[tid];
        float mx = v;
        for (int off = 32; off; off >>= 1) mx = fmaxf(mx, __shfl_xor(mx, off));
        if ((tid & 63) == 0) sRed[tid >> 6] = mx;
        __syncthreads();
        mx = sRed[0];
#pragma unroll
        for (int w = 1; w < 8; w++) mx = fmaxf(mx, sRed[w]);
        float e = expf(v - mx);
        float sm = e;
        for (int off = 32; off; off >>= 1) sm += __shfl_xor(sm, off);
        if ((tid & 63) == 0) sRed2[tid >> 6] = sm;
        __syncthreads();
        sm = 0.f;
#pragma unroll
        for (int w = 0; w < 8; w++) sm += sRed2[w];
        sLogit[tid] = e / sm;
    }
    __syncthreads();
    // ---- p ----
    {
        int gq = tid >> 7, m = tid & 127;
        float pp = 0.f;
        for (int l = gq * 128; l < gq * 128 + 128; l++)
            pp += sLogit[l] * bf2f(t2b[l * 128 + m]);
        sPc[gq][m] = pp;
    }
    __syncthreads();
    if (tid < 128)
        sCin[128 + tid] = sPc[0][tid] + sPc[1][tid] + sPc[2][tid] + sPc[3][tid];
    __syncthreads();

    // ---- head MLP: relu(relu(cin@W1+b1)@W2+b2)@outW + outb ----
    float* sH1 = (float*)&sT[0][0];       // 1024 floats (sT dead)
    float* sH2 = sH1 + 1024;              // 512 floats
#pragma unroll
    for (int j = 0; j < 2; j++) {
        int n = tid + j * 512;
        float a = cat1_b[n];
        for (int k = 0; k < 256; k++) a = fmaf(sCin[k], cat1_W[k * 1024 + n], a);
        sH1[n] = fmaxf(a, 0.f);
    }
    __syncthreads();
    {
        float a = cat2_b[tid];
        for (int k = 0; k < 1024; k++) a = fmaf(sH1[k], cat2_W[k * 512 + tid], a);
        sH2[tid] = fmaxf(a, 0.f);
    }
    __syncthreads();
    {
        float a = sH2[tid] * outW[tid];
        for (int off = 32; off; off >>= 1) a += __shfl_xor(a, off);
        if ((tid & 63) == 0) sRed[tid >> 6] = a;
        __syncthreads();
        if (tid == 0) {
            float s = 0.f;
#pragma unroll
            for (int w = 0; w < 8; w++) s += sRed[w];
            out[b] = s + outb[0];
        }
    }
}

extern "C" void kernel_launch(void* const* d_in, const int* in_sizes, int n_in,
                              void* d_out, int out_size, void* d_ws, size_t ws_size,
                              hipStream_t stream) {
    const float* x        = (const float*)d_in[0];
    const int*   ei       = (const int*)d_in[1];
    const int*   tgt      = (const int*)d_in[2];
    const float* proteins = (const float*)d_in[4];
    const float* gW1 = (const float*)d_in[5];  const float* gb1 = (const float*)d_in[6];
    const float* gW2 = (const float*)d_in[7];  const float* gb2 = (const float*)d_in[8];
    const float* gW3 = (const float*)d_in[9];  const float* gb3 = (const float*)d_in[10];
    const float* fc1_W = (const float*)d_in[11]; const float* fc1_b = (const float*)d_in[12];
    const float* fc2_W = (const float*)d_in[13]; const float* fc2_b = (const float*)d_in[14];
    const float* bert1_W = (const float*)d_in[15]; const float* bert1_b = (const float*)d_in[16];
    const float* bert2_W = (const float*)d_in[17]; const float* bert2_b = (const float*)d_in[18];
    const float* W_b = (const float*)d_in[19];
    const float* W_c = (const float*)d_in[20];
    const float* W_p = (const float*)d_in[21];
    const float* w_hc = (const float*)d_in[22];
    const float* w_hp = (const float*)d_in[23];
    const float* cat1_W = (const float*)d_in[24]; const float* cat1_b = (const float*)d_in[25];
    const float* cat2_W = (const float*)d_in[26]; const float* cat2_b = (const float*)d_in[27];
    const float* out_W = (const float*)d_in[28]; const float* out_b = (const float*)d_in[29];

    // ---- workspace layout ----
    char* w = (char*)d_ws;
    auto alloc = [&](size_t bytes) -> void* {
        void* p = (void*)w;
        w += (bytes + 255) & ~(size_t)255;
        return p;
    };
    float* hd        = (float*)alloc((size_t)5760 * 256 * 4);
    bf16*  fc1o      = (bf16*)alloc((size_t)5760 * 1024 * 2);
    float* hd2       = (float*)alloc((size_t)5760 * 128 * 4);
    bf16*  t1        = (bf16*)alloc((size_t)65536 * 128 * 2);
    bf16*  t2        = (bf16*)alloc((size_t)65536 * 128 * 2);
    ushort* fc1_WT   = (ushort*)alloc((size_t)1024 * 256 * 2);
    ushort* fc2_WT   = (ushort*)alloc((size_t)128 * 1024 * 2);
    ushort* bert1_WT = (ushort*)alloc((size_t)128 * 1280 * 2);
    ushort* bert2_WT = (ushort*)alloc((size_t)128 * 128 * 2);

    // 1. fused prep: transposes + per-graph CSR + 3-layer GCN -> hd
    k_prep<<<NB + 560, 256, 0, stream>>>(x, ei, gW1, gb1, gW2, gb2, gW3, gb3, hd,
                                         fc1_W, fc2_W, bert1_W, bert2_W,
                                         fc1_WT, fc2_WT, bert1_WT, bert2_WT);
    // 2-3. dense graph MLP (MFMA)
    gemm_mfma<float, bf16, 1, false><<<dim3(45, 8), 256, 0, stream>>>(hd, fc1_WT, fc1_b, fc1o, 5760, 1024, 256, nullptr);
    gemm_mfma64<<<dim3(90, 2), 256, 0, stream>>>((const ushort*)fc1o, fc2_WT, fc2_b, hd2, 5760, 128, 1024);
    // 4-5. protein branch (MFMA; gather fused into bert1 A-staging)
    gemm_mfma<float, bf16, 1, true><<<dim3(512, 1), 256, 0, stream>>>(proteins, bert1_WT, bert1_b, t1, 65536, 128, 1280, tgt);
    gemm_mfma<ushort, bf16, 1, false><<<dim3(512, 1), 256, 0, stream>>>((const ushort*)t1, bert2_WT, bert2_b, t2, 65536, 128, 128, nullptr);
    // 6. fused co-attention + head -> out
    k_coatt_head<<<NB, 512, 0, stream>>>((const ushort*)t2, hd2, W_b, W_c, W_p, w_hc, w_hp,
                                         cat1_W, cat1_b, cat2_W, cat2_b, out_W, out_b,
                                         (float*)d_out);
}

// Round 6
// 1151.899 us; speedup vs baseline: 2.0053x; 1.0112x over previous
//
#include <hip/hip_runtime.h>
#include <hip/hip_bf16.h>

typedef __hip_bfloat16 bf16;
typedef __bf16 bf16x8 __attribute__((ext_vector_type(8)));
typedef float f32x4 __attribute__((ext_vector_type(4)));

#define NB   128   // graphs
#define NPGX 40    // nodes per graph
#define NNODE 5120 // total nodes
#define NE   20000 // edges
#define LPX  512   // protein seq len
#define MAXNX 45
#define EMAX 512   // per-graph edge cap

__device__ __forceinline__ ushort f2bf(float f) {
    uint x = __float_as_uint(f);
    return (ushort)((x + 0x7fffu + ((x >> 16) & 1u)) >> 16);
}
__device__ __forceinline__ float bf2f(ushort u) { return __uint_as_float(((uint)u) << 16); }
__device__ __forceinline__ float dot4(f32x4 a, f32x4 b) {
    return a[0]*b[0] + a[1]*b[1] + a[2]*b[2] + a[3]*b[3];
}

// =================== dispatch 1: GCN (blocks 0..127) + weight transposes (128..687) ===================
__device__ __forceinline__ void gcn_gemm(const float (*hin)[132], float (*hout)[260],
                                         float (*sW)[260], const float* __restrict__ Wg,
                                         int K, int N, int NQ, int t) {
    f32x4 acc[10] = {};
    for (int k0 = 0; k0 < K; k0 += 32) {
        int kmax = min(32, K - k0);
        int kpad = (kmax + 3) & ~3;
        __syncthreads();
        for (int o = t; o < kpad * N; o += 256) {
            int row = o / N, c = o - row * N;
            sW[row][c] = (row < kmax) ? Wg[(k0 + row) * N + c] : 0.f;
        }
        __syncthreads();
        for (int kk = 0; kk < kpad; kk += 4) {
#pragma unroll 10
            for (int j = 0; j < NQ; j++) {
                int q = t + j * 256;
                int i = q / (N / 4), f = (q % (N / 4)) * 4;
                f32x4 hv = *(const f32x4*)&hin[i][k0 + kk];
#pragma unroll
                for (int d = 0; d < 4; d++) {
                    f32x4 wv = *(const f32x4*)&sW[kk + d][f];
                    acc[j][0] = fmaf(hv[d], wv[0], acc[j][0]);
                    acc[j][1] = fmaf(hv[d], wv[1], acc[j][1]);
                    acc[j][2] = fmaf(hv[d], wv[2], acc[j][2]);
                    acc[j][3] = fmaf(hv[d], wv[3], acc[j][3]);
                }
            }
        }
    }
    __syncthreads();
#pragma unroll 10
    for (int j = 0; j < NQ; j++) {
        int q = t + j * 256;
        int i = q / (N / 4), f = (q % (N / 4)) * 4;
        *(f32x4*)&hout[i][f] = acc[j];
    }
}

__device__ __forceinline__ void gcn_agg(const float (*hout)[260], float (*hin)[132],
                                        const float* __restrict__ bias,
                                        const float* __restrict__ dgi,
                                        const int* __restrict__ rs,
                                        const int* __restrict__ colv,
                                        const float* __restrict__ valv,
                                        float* __restrict__ hd, int N, bool tohd, int g, int t) {
    for (int o = t; o < 40 * N; o += 256) {
        int i = o / N, f = o - i * N;
        float s = hout[i][f] * dgi[i];
        int e0 = rs[i], e1 = rs[i + 1];
        for (int e = e0; e < e1; e++) s += valv[e] * hout[colv[e]][f];
        s += bias[f];
        s = fmaxf(s, 0.f);
        if (tohd) hd[(g * MAXNX + i) * N + f] = s;
        else      hin[i][f] = s;
    }
    if (tohd) for (int o = t; o < 5 * N; o += 256) hd[(g * MAXNX + 40) * N + o] = 0.f;
}

__global__ __launch_bounds__(256) void k_gcn_tr(
    const float* __restrict__ x, const int* __restrict__ ei,
    const float* __restrict__ W1, const float* __restrict__ b1,
    const float* __restrict__ W2, const float* __restrict__ b2,
    const float* __restrict__ W3, const float* __restrict__ b3,
    float* __restrict__ hd,
    const float* __restrict__ ws0, const float* __restrict__ ws1,
    const float* __restrict__ ws2, const float* __restrict__ ws3,
    ushort* __restrict__ wd0, ushort* __restrict__ wd1,
    ushort* __restrict__ wd2, ushort* __restrict__ wd3)
{
    __shared__ __align__(16) float hin[40][132];
    __shared__ __align__(16) float hout[40][260];
    __shared__ __align__(16) float sW[32][260];
    __shared__ int   s_cnt[40], s_cur[40], s_rs[41];
    __shared__ int   s_col[EMAX];
    __shared__ float s_val[EMAX];
    __shared__ float s_dinv[40], s_dgi[40];

    const int t = threadIdx.x;

    if (blockIdx.x >= NB) {
        float (*ts)[33] = reinterpret_cast<float(*)[33]>(&hin[0][0]);
        int bid = blockIdx.x - NB;
        const float* in; ushort* out; int K, N, b;
        if (bid < 256)      { in = ws0; out = wd0; K = 256;  N = 1024; b = bid; }        // fc1_W
        else if (bid < 384) { in = ws1; out = wd1; K = 1024; N = 128;  b = bid - 256; }  // fc2_W
        else if (bid < 544) { in = ws2; out = wd2; K = 1280; N = 128;  b = bid - 384; }  // bert1
        else                { in = ws3; out = wd3; K = 128;  N = 128;  b = bid - 544; }  // bert2
        int ktiles = K / 32;
        int kt = (b % ktiles) * 32, nt = (b / ktiles) * 32;
        int tn = t & 31, tk = t >> 5;
#pragma unroll
        for (int i = 0; i < 4; i++)
            ts[tk + i * 8][tn] = in[(long)(kt + tk + i * 8) * N + nt + tn];
        __syncthreads();
#pragma unroll
        for (int i = 0; i < 4; i++)
            out[(long)(nt + tk + i * 8) * K + kt + tn] = f2bf(ts[tn][tk + i * 8]);
        return;
    }

    const int g = blockIdx.x;
    const int base = g * NPGX;
    const int* srcp = ei;
    const int* dstp = ei + NE;

    for (int o = t; o < 40; o += 256) { s_cnt[o] = 0; s_cur[o] = 0; }
    for (int o = t; o < 40 * 78; o += 256) hin[o / 78][o % 78] = x[base * 78 + o];
    for (int o = t; o < 80; o += 256) hin[o >> 1][78 + (o & 1)] = 0.f;
    __syncthreads();
    for (int e = t; e < NE; e += 256) {
        int dl = dstp[e] - base;
        if ((unsigned)dl < 40u) atomicAdd(&s_cnt[dl], 1);
    }
    __syncthreads();
    if (t == 0) {
        int acc = 0;
        for (int i = 0; i < 40; i++) { s_rs[i] = acc; acc += s_cnt[i]; }
        s_rs[40] = acc;
    }
    if (t < 40) {
        float deg = (float)(s_cnt[t] + 1);
        s_dinv[t] = rsqrtf(deg);
        s_dgi[t] = 1.f / deg;
    }
    __syncthreads();
    for (int e = t; e < NE; e += 256) {
        int dl = dstp[e] - base;
        if ((unsigned)dl < 40u) {
            int sl = srcp[e] - base;
            int p = atomicAdd(&s_cur[dl], 1);
            int idx = s_rs[dl] + p;
            if (idx < EMAX) { s_col[idx] = sl; s_val[idx] = s_dinv[sl] * s_dinv[dl]; }
        }
    }
    __syncthreads();

    gcn_gemm(hin, hout, sW, W1, 78, 128, 5, t);
    __syncthreads();
    gcn_agg(hout, hin, b1, s_dgi, s_rs, s_col, s_val, nullptr, 128, false, g, t);
    __syncthreads();
    gcn_gemm(hin, hout, sW, W2, 128, 128, 5, t);
    __syncthreads();
    gcn_agg(hout, hin, b2, s_dgi, s_rs, s_col, s_val, nullptr, 128, false, g, t);
    __syncthreads();
    gcn_gemm(hin, hout, sW, W3, 128, 256, 10, t);
    __syncthreads();
    gcn_agg(hout, nullptr, b3, s_dgi, s_rs, s_col, s_val, hd, 256, true, g, t);
}

// =================== dispatch 2: k_main — bert1+bert2 fused (blocks 0..511) + fc1 (512..871) ===================
__global__ __launch_bounds__(256) void k_main(
    const float* __restrict__ proteins, const int* __restrict__ tgt,
    const ushort* __restrict__ bert1_WT, const float* __restrict__ bert1_b,
    const ushort* __restrict__ bert2_WT, const float* __restrict__ bert2_b,
    const float* __restrict__ hd, const ushort* __restrict__ fc1_WT,
    const float* __restrict__ fc1_b,
    ushort* __restrict__ t2, ushort* __restrict__ fc1o)
{
    // LDS layout: [uT1: 128x136 bf16 = 34816B (uA overlays first 10240B)][uB: 128x40 bf16 = 10240B]
    __shared__ __align__(16) char smem[45056];
    ushort (*uA)[40]   = (ushort(*)[40])smem;
    ushort (*uT1)[136] = (ushort(*)[136])smem;
    ushort (*uB)[40]   = (ushort(*)[40])(smem + 34816);

    const int t = threadIdx.x;
    const int lane = t & 63, wave = t >> 6;
    const int wr = wave >> 1, wc = wave & 1;
    const int fr = lane & 15, kh = lane >> 4;

    if (blockIdx.x < 512) {
        // ---------------- bert1 + bert2 fused ----------------
        const int m0 = blockIdx.x * 128;
        f32x4 acc[4][4] = {};
        for (int k0 = 0; k0 < 1280; k0 += 32) {
            // stage A: gathered proteins fp32 -> bf16
#pragma unroll
            for (int i = 0; i < 4; i++) {
                int linear = i * 1024 + t * 4;
                int row = linear >> 5, k = linear & 31;
                long gr = m0 + row;
                int bb = (int)(gr >> 9); gr = (long)tgt[bb] * LPX + (gr & 511);
                float4 v = *(const float4*)(proteins + gr * 1280L + k0 + k);
                ushort4 h;
                h.x = f2bf(v.x); h.y = f2bf(v.y); h.z = f2bf(v.z); h.w = f2bf(v.w);
                *(ushort4*)&uA[row][k] = h;
            }
            // stage B from bert1_WT [128][1280]
#pragma unroll
            for (int i = 0; i < 2; i++) {
                int linear = i * 2048 + t * 8;
                int row = linear >> 5, k = linear & 31;
                *(uint4*)&uB[row][k] = *(const uint4*)(bert1_WT + (long)row * 1280 + k0 + k);
            }
            __syncthreads();
            bf16x8 a[4], b[4];
#pragma unroll
            for (int mf = 0; mf < 4; mf++)
                a[mf] = *(const bf16x8*)&uA[wr * 64 + mf * 16 + fr][kh * 8];
#pragma unroll
            for (int nf = 0; nf < 4; nf++)
                b[nf] = *(const bf16x8*)&uB[wc * 64 + nf * 16 + fr][kh * 8];
#pragma unroll
            for (int mf = 0; mf < 4; mf++)
#pragma unroll
                for (int nf = 0; nf < 4; nf++)
                    acc[mf][nf] = __builtin_amdgcn_mfma_f32_16x16x32_bf16(a[mf], b[nf], acc[mf][nf], 0, 0, 0);
            __syncthreads();
        }
        // epilogue 1: t1 = relu(acc + bert1_b) -> uT1 (overlays uA; safe after final sync)
#pragma unroll
        for (int mf = 0; mf < 4; mf++)
#pragma unroll
            for (int nf = 0; nf < 4; nf++) {
                int col = wc * 64 + nf * 16 + fr;
                float bv = bert1_b[col];
#pragma unroll
                for (int r = 0; r < 4; r++) {
                    int row = wr * 64 + mf * 16 + kh * 4 + r;
                    uT1[row][col] = f2bf(fmaxf(acc[mf][nf][r] + bv, 0.f));
                }
            }
        __syncthreads();
        // phase 2: t2 = relu(t1 @ bert2_WT^T + bert2_b)
        f32x4 acc2[4][4] = {};
        for (int ks = 0; ks < 4; ks++) {
#pragma unroll
            for (int j = 0; j < 2; j++) {
                int i2 = t + j * 256;
                int row = i2 >> 2, q = (i2 & 3) * 8;
                *(uint4*)&uB[row][q] = *(const uint4*)(bert2_WT + (long)row * 128 + ks * 32 + q);
            }
            __syncthreads();
            bf16x8 a[4], b[4];
#pragma unroll
            for (int mf = 0; mf < 4; mf++)
                a[mf] = *(const bf16x8*)&uT1[wr * 64 + mf * 16 + fr][ks * 32 + kh * 8];
#pragma unroll
            for (int nf = 0; nf < 4; nf++)
                b[nf] = *(const bf16x8*)&uB[wc * 64 + nf * 16 + fr][kh * 8];
#pragma unroll
            for (int mf = 0; mf < 4; mf++)
#pragma unroll
                for (int nf = 0; nf < 4; nf++)
                    acc2[mf][nf] = __builtin_amdgcn_mfma_f32_16x16x32_bf16(a[mf], b[nf], acc2[mf][nf], 0, 0, 0);
            __syncthreads();
        }
#pragma unroll
        for (int mf = 0; mf < 4; mf++)
#pragma unroll
            for (int nf = 0; nf < 4; nf++) {
                int col = wc * 64 + nf * 16 + fr;
                float bv = bert2_b[col];
#pragma unroll
                for (int r = 0; r < 4; r++) {
                    int row = m0 + wr * 64 + mf * 16 + kh * 4 + r;
                    t2[(long)row * 128 + col] = f2bf(fmaxf(acc2[mf][nf][r] + bv, 0.f));
                }
            }
    } else {
        // ---------------- fc1 tile: fc1o = relu(hd @ fc1_WT^T + fc1_b) ----------------
        int ft = blockIdx.x - 512;
        const int m0 = (ft % 45) * 128;
        const int n0 = (ft / 45) * 128;
        f32x4 acc[4][4] = {};
        for (int k0 = 0; k0 < 256; k0 += 32) {
#pragma unroll
            for (int i = 0; i < 4; i++) {
                int linear = i * 1024 + t * 4;
                int row = linear >> 5, k = linear & 31;
                float4 v = *(const float4*)(hd + (long)(m0 + row) * 256 + k0 + k);
                ushort4 h;
                h.x = f2bf(v.x); h.y = f2bf(v.y); h.z = f2bf(v.z); h.w = f2bf(v.w);
                *(ushort4*)&uA[row][k] = h;
            }
#pragma unroll
            for (int i = 0; i < 2; i++) {
                int linear = i * 2048 + t * 8;
                int row = linear >> 5, k = linear & 31;
                *(uint4*)&uB[row][k] = *(const uint4*)(fc1_WT + (long)(n0 + row) * 256 + k0 + k);
            }
            __syncthreads();
            bf16x8 a[4], b[4];
#pragma unroll
            for (int mf = 0; mf < 4; mf++)
                a[mf] = *(const bf16x8*)&uA[wr * 64 + mf * 16 + fr][kh * 8];
#pragma unroll
            for (int nf = 0; nf < 4; nf++)
                b[nf] = *(const bf16x8*)&uB[wc * 64 + nf * 16 + fr][kh * 8];
#pragma unroll
            for (int mf = 0; mf < 4; mf++)
#pragma unroll
                for (int nf = 0; nf < 4; nf++)
                    acc[mf][nf] = __builtin_amdgcn_mfma_f32_16x16x32_bf16(a[mf], b[nf], acc[mf][nf], 0, 0, 0);
            __syncthreads();
        }
#pragma unroll
        for (int mf = 0; mf < 4; mf++)
#pragma unroll
            for (int nf = 0; nf < 4; nf++) {
                int col = n0 + wc * 64 + nf * 16 + fr;
                float bv = fc1_b[col];
#pragma unroll
                for (int r = 0; r < 4; r++) {
                    int row = m0 + wr * 64 + mf * 16 + kh * 4 + r;
                    fc1o[(long)row * 1024 + col] = f2bf(fmaxf(acc[mf][nf][r] + bv, 0.f));
                }
            }
    }
}

// =================== dispatch 3: fc2-in-block + co-attention + head, one block (512 thr) per graph ===================
__global__ __launch_bounds__(512) void k_coatt_head(
    const ushort* __restrict__ t2, const ushort* __restrict__ fc1o,
    const ushort* __restrict__ fc2_WT, const float* __restrict__ fc2_b,
    const float* __restrict__ W_b, const float* __restrict__ W_c,
    const float* __restrict__ W_p, const float* __restrict__ w_hc,
    const float* __restrict__ w_hp,
    const float* __restrict__ cat1_W, const float* __restrict__ cat1_b,
    const float* __restrict__ cat2_W, const float* __restrict__ cat2_b,
    const float* __restrict__ outW, const float* __restrict__ outb,
    float* __restrict__ out)
{
    __shared__ __align__(16) float  sx[48][132];    // hd2 rows (45 used; 45..47 zero)
    __shared__ __align__(16) ushort sY[48][136];
    __shared__ __align__(16) ushort sWpb[32][136];
    __shared__ __align__(16) float  sWcx[32][48];
    __shared__ __align__(16) float  sHc[32][48];
    __shared__ __align__(16) ushort sT[128][136];   // fc2 staging -> t2 chunks -> head scratch
    __shared__ __align__(16) float  sC[128][52];
    __shared__ __align__(16) float  sWpt[32][132];
    __shared__ float  sLogit[512];
    __shared__ float  sLc[64];
    __shared__ float  swh[64];
    __shared__ float  sRed[8], sRed2[8];
    __shared__ float  sPc[4][128];
    __shared__ float  sCin[256];

    const int b = blockIdx.x, tid = threadIdx.x;
    const int lane = tid & 63, wave = tid >> 6;
    const int fr = lane & 15, kh = lane >> 4;

    // ---- init (no sx load: computed by fc2 phase below) ----
    for (int o = tid; o < 32 * 32; o += 512) {
        int r = o >> 5, q = (o & 31) * 4;
        f32x4 v = *(const f32x4*)&W_p[r * 128 + q];
        sWpb[r][q] = f2bf(v[0]); sWpb[r][q + 1] = f2bf(v[1]);
        sWpb[r][q + 2] = f2bf(v[2]); sWpb[r][q + 3] = f2bf(v[3]);
    }
    if (tid < 64) swh[tid] = (tid < 32) ? w_hc[tid] : w_hp[tid - 32];
    for (int o = tid; o < 32 * 12; o += 512) {
        int r = o / 12, q = (o - r * 12) * 4;
        *(f32x4*)&sHc[r][q] = f32x4{0.f, 0.f, 0.f, 0.f};
    }
    if (tid < 96) {  // zero sx rows 45..47 (cols 0..127)
        int r = 45 + tid / 32, q = (tid & 31) * 4;
        *(f32x4*)&sx[r][q] = f32x4{0.f, 0.f, 0.f, 0.f};
    }

    // ---- fc2 in-block: sx[0..44][:] = relu(fc1o[b*45+s,:1024] @ fc2_WT^T + fc2_b) via MFMA ----
    {
        ushort (*sA2)[40] = (ushort(*)[40])&sT[0][0];                 // 48x40  (3840B)
        ushort (*sB2)[40] = (ushort(*)[40])((char*)&sT[0][0] + 4096); // 128x40 (10240B)
        f32x4 acc2[3] = {};
        for (int k0 = 0; k0 < 1024; k0 += 32) {
            if (tid < 192) {          // A: 48 rows x 32 k  (rows 45..47 read next graph / in-bounds; masked)
                int row = tid >> 2, q = (tid & 3) * 8;
                *(uint4*)&sA2[row][q] = *(const uint4*)(fc1o + (size_t)(b * 45 + row) * 1024 + k0 + q);
            }
            {                          // B: 128 rows x 32 k
                int row = tid >> 2, q = (tid & 3) * 8;
                *(uint4*)&sB2[row][q] = *(const uint4*)(fc2_WT + (size_t)row * 1024 + k0 + q);
            }
            __syncthreads();
            bf16x8 bfr = *(const bf16x8*)&sB2[wave * 16 + fr][kh * 8];
#pragma unroll
            for (int mf = 0; mf < 3; mf++) {
                bf16x8 afr = *(const bf16x8*)&sA2[mf * 16 + fr][kh * 8];
                acc2[mf] = __builtin_amdgcn_mfma_f32_16x16x32_bf16(afr, bfr, acc2[mf], 0, 0, 0);
            }
            __syncthreads();
        }
#pragma unroll
        for (int mf = 0; mf < 3; mf++) {
            int col = wave * 16 + fr;
            float bv = fc2_b[col];
#pragma unroll
            for (int r = 0; r < 4; r++) {
                int row = mf * 16 + kh * 4 + r;
                if (row < 45) sx[row][col] = fmaxf(acc2[mf][r] + bv, 0.f);
            }
        }
    }
    __syncthreads();

    // ---- Y[s][k] = sum_m W_b[k][m]*hd2[s][m]  (2k x 6s per thread) ----
    {
        int kg = tid >> 3, sg = tid & 7;
        float acc[12] = {};
        for (int m = 0; m < 128; m += 4) {
            f32x4 w0 = *(const f32x4*)&W_b[(2 * kg) * 128 + m];
            f32x4 w1 = *(const f32x4*)&W_b[(2 * kg + 1) * 128 + m];
#pragma unroll
            for (int u = 0; u < 6; u++) {
                f32x4 xv = *(const f32x4*)&sx[6 * sg + u][m];
                acc[u] += dot4(w0, xv);
                acc[6 + u] += dot4(w1, xv);
            }
        }
#pragma unroll
        for (int u = 0; u < 6; u++) {
            int s = 6 * sg + u;
            sY[s][2 * kg] = f2bf(acc[u]);
            sY[s][2 * kg + 1] = f2bf(acc[6 + u]);
        }
    }
    // ---- Wcx[k][s] ----
    if (tid < 256) {
        int k = tid >> 3, sg = tid & 7;
        float acc[6] = {};
        for (int m = 0; m < 128; m += 4) {
            f32x4 w = *(const f32x4*)&W_c[k * 128 + m];
#pragma unroll
            for (int u = 0; u < 6; u++) {
                f32x4 xv = *(const f32x4*)&sx[6 * sg + u][m];
                acc[u] += dot4(w, xv);
            }
        }
#pragma unroll
        for (int u = 0; u < 6; u++) sWcx[k][6 * sg + u] = acc[u];
    }
    __syncthreads();

    const ushort* t2b = t2 + ((size_t)b * 512) * 128;

    for (int lc = 0; lc < 4; lc++) {
        {
            const ushort* srcp = t2b + lc * 128 * 128;
#pragma unroll
            for (int i = 0; i < 4; i++) {
                int idx = tid + i * 512;
                int row = idx >> 4, c8 = (idx & 15) * 8;
                *(uint4*)&sT[row][c8] = *(const uint4*)(srcp + row * 128 + c8);
            }
        }
        __syncthreads();
        // MFMA: C (3 n-tiles) + Wpt (2 m-tiles)
        {
            f32x4 cacc[3] = {};
            f32x4 wacc[2] = {};
#pragma unroll
            for (int ks = 0; ks < 4; ks++) {
                bf16x8 af = *(const bf16x8*)&sT[wave * 16 + fr][ks * 32 + kh * 8];
#pragma unroll
                for (int nt = 0; nt < 3; nt++) {
                    bf16x8 bf = *(const bf16x8*)&sY[nt * 16 + fr][ks * 32 + kh * 8];
                    cacc[nt] = __builtin_amdgcn_mfma_f32_16x16x32_bf16(af, bf, cacc[nt], 0, 0, 0);
                }
#pragma unroll
                for (int mt = 0; mt < 2; mt++) {
                    bf16x8 aw = *(const bf16x8*)&sWpb[mt * 16 + fr][ks * 32 + kh * 8];
                    wacc[mt] = __builtin_amdgcn_mfma_f32_16x16x32_bf16(aw, af, wacc[mt], 0, 0, 0);
                }
            }
#pragma unroll
            for (int nt = 0; nt < 3; nt++)
#pragma unroll
                for (int r = 0; r < 4; r++)
                    sC[wave * 16 + kh * 4 + r][nt * 16 + fr] = tanhf(cacc[nt][r]);
#pragma unroll
            for (int mt = 0; mt < 2; mt++)
#pragma unroll
                for (int r = 0; r < 4; r++)
                    sWpt[mt * 16 + kh * 4 + r][wave * 16 + fr] = wacc[mt][r];
        }
        __syncthreads();
        // Hc accumulate (384 thr, vectorized Wpt reads) + Hp partials (all threads)
        float hpacc[8];
        {
            if (tid < 384) {
                int k = tid / 12, sg = tid - (tid / 12) * 12;
                f32x4 a = {0.f, 0.f, 0.f, 0.f};
                for (int l4 = 0; l4 < 128; l4 += 4) {
                    f32x4 wv4 = *(const f32x4*)&sWpt[k][l4];
#pragma unroll
                    for (int d = 0; d < 4; d++) {
                        f32x4 cv = *(const f32x4*)&sC[l4 + d][sg * 4];
                        a[0] = fmaf(wv4[d], cv[0], a[0]); a[1] = fmaf(wv4[d], cv[1], a[1]);
                        a[2] = fmaf(wv4[d], cv[2], a[2]); a[3] = fmaf(wv4[d], cv[3], a[3]);
                    }
                }
                f32x4 h = *(const f32x4*)&sHc[k][sg * 4];
                h[0] += a[0]; h[1] += a[1]; h[2] += a[2]; h[3] += a[3];
                *(f32x4*)&sHc[k][sg * 4] = h;
            }
            int kg = tid >> 5, li = tid & 31;
            float acc[8] = {};
            for (int s4 = 0; s4 < 48; s4 += 4) {
                f32x4 w0 = *(const f32x4*)&sWcx[2 * kg][s4];
                f32x4 w1 = *(const f32x4*)&sWcx[2 * kg + 1][s4];
#pragma unroll
                for (int u = 0; u < 4; u++) {
                    f32x4 cv = *(const f32x4*)&sC[li + 32 * u][s4];
                    acc[u] += dot4(w0, cv);
                    acc[4 + u] += dot4(w1, cv);
                }
            }
#pragma unroll
            for (int u = 0; u < 8; u++) hpacc[u] = acc[u];
        }
        __syncthreads();
        // Hp in-place
        {
            int kg = tid >> 5, li = tid & 31;
#pragma unroll
            for (int u = 0; u < 4; u++) {
                sWpt[2 * kg][li + 32 * u] = tanhf(sWpt[2 * kg][li + 32 * u] + hpacc[u]);
                sWpt[2 * kg + 1][li + 32 * u] = tanhf(sWpt[2 * kg + 1][li + 32 * u] + hpacc[4 + u]);
            }
        }
        __syncthreads();
        // ap logits
        if (tid < 128) {
            float a = 0.f;
            for (int k = 0; k < 32; k++) a += swh[32 + k] * sWpt[k][tid];
            sLogit[lc * 128 + tid] = a;
        }
        __syncthreads();
    }

    // ---- Hc finalize ----
    {
        int k = tid >> 4, si = tid & 15;
        sHc[k][si] = tanhf(sWcx[k][si] + sHc[k][si]);
        sHc[k][si + 16] = tanhf(sWcx[k][si + 16] + sHc[k][si + 16]);
        sHc[k][si + 32] = tanhf(sWcx[k][si + 32] + sHc[k][si + 32]);
    }
    __syncthreads();
    if (tid < 45) {
        float a = 0.f;
        for (int k = 0; k < 32; k++) a += swh[k] * sHc[k][tid];
        sLc[tid] = a;
    }
    __syncthreads();
    if (tid < 64) {
        float v = (tid < 45) ? sLc[tid] : -1e30f;
        float mx = v;
        for (int off = 32; off; off >>= 1) mx = fmaxf(mx, __shfl_xor(mx, off));
        float e = (tid < 45) ? expf(v - mx) : 0.f;
        float sm = e;
        for (int off = 32; off; off >>= 1) sm += __shfl_xor(sm, off);
        if (tid < 45) sLc[tid] = e / sm;
    }
    __syncthreads();
    if (tid < 128) {
        float c = 0.f;
        for (int s = 0; s < 45; s++) c += sLc[s] * sx[s][tid];
        sCin[tid] = c;
    }
    // ---- ap softmax over 512 ----
    {
        float v = sLogit[tid];
        float mx = v;
        for (int off = 32; off; off >>= 1) mx = fmaxf(mx, __shfl_xor(mx, off));
        if ((tid & 63) == 0) sRed[tid >> 6] = mx;
        __syncthreads();
        mx = sRed[0];
#pragma unroll
        for (int w = 1; w < 8; w++) mx = fmaxf(mx, sRed[w]);
        float e = expf(v - mx);
        float sm = e;
        for (int off = 32; off; off >>= 1) sm += __shfl_xor(sm, off);
        if ((tid & 63) == 0) sRed2[tid >> 6] = sm;
        __syncthreads();
        sm = 0.f;
#pragma unroll
        for (int w = 0; w < 8; w++) sm += sRed2[w];
        sLogit[tid] = e / sm;
    }
    __syncthreads();
    {
        int gq = tid >> 7, m = tid & 127;
        float pp = 0.f;
        for (int l = gq * 128; l < gq * 128 + 128; l++)
            pp += sLogit[l] * bf2f(t2b[l * 128 + m]);
        sPc[gq][m] = pp;
    }
    __syncthreads();
    if (tid < 128)
        sCin[128 + tid] = sPc[0][tid] + sPc[1][tid] + sPc[2][tid] + sPc[3][tid];
    __syncthreads();

    // ---- head MLP ----
    float* sH1 = (float*)&sT[0][0];
    float* sH2 = sH1 + 1024;
#pragma unroll
    for (int j = 0; j < 2; j++) {
        int n = tid + j * 512;
        float a = cat1_b[n];
        for (int k = 0; k < 256; k++) a = fmaf(sCin[k], cat1_W[k * 1024 + n], a);
        sH1[n] = fmaxf(a, 0.f);
    }
    __syncthreads();
    {
        float a = cat2_b[tid];
        for (int k = 0; k < 1024; k++) a = fmaf(sH1[k], cat2_W[k * 512 + tid], a);
        sH2[tid] = fmaxf(a, 0.f);
    }
    __syncthreads();
    {
        float a = sH2[tid] * outW[tid];
        for (int off = 32; off; off >>= 1) a += __shfl_xor(a, off);
        if ((tid & 63) == 0) sRed[tid >> 6] = a;
        __syncthreads();
        if (tid == 0) {
            float s = 0.f;
#pragma unroll
            for (int w = 0; w < 8; w++) s += sRed[w];
            out[b] = s + outb[0];
        }
    }
}

extern "C" void kernel_launch(void* const* d_in, const int* in_sizes, int n_in,
                              void* d_out, int out_size, void* d_ws, size_t ws_size,
                              hipStream_t stream) {
    const float* x        = (const float*)d_in[0];
    const int*   ei       = (const int*)d_in[1];
    const int*   tgt      = (const int*)d_in[2];
    const float* proteins = (const float*)d_in[4];
    const float* gW1 = (const float*)d_in[5];  const float* gb1 = (const float*)d_in[6];
    const float* gW2 = (const float*)d_in[7];  const float* gb2 = (const float*)d_in[8];
    const float* gW3 = (const float*)d_in[9];  const float* gb3 = (const float*)d_in[10];
    const float* fc1_W = (const float*)d_in[11]; const float* fc1_b = (const float*)d_in[12];
    const float* fc2_W = (const float*)d_in[13]; const float* fc2_b = (const float*)d_in[14];
    const float* bert1_W = (const float*)d_in[15]; const float* bert1_b = (const float*)d_in[16];
    const float* bert2_W = (const float*)d_in[17]; const float* bert2_b = (const float*)d_in[18];
    const float* W_b = (const float*)d_in[19];
    const float* W_c = (const float*)d_in[20];
    const float* W_p = (const float*)d_in[21];
    const float* w_hc = (const float*)d_in[22];
    const float* w_hp = (const float*)d_in[23];
    const float* cat1_W = (const float*)d_in[24]; const float* cat1_b = (const float*)d_in[25];
    const float* cat2_W = (const float*)d_in[26]; const float* cat2_b = (const float*)d_in[27];
    const float* out_W = (const float*)d_in[28]; const float* out_b = (const float*)d_in[29];

    // ---- workspace layout ----
    char* w = (char*)d_ws;
    auto alloc = [&](size_t bytes) -> void* {
        void* p = (void*)w;
        w += (bytes + 255) & ~(size_t)255;
        return p;
    };
    float*  hd        = (float*)alloc((size_t)5760 * 256 * 4);
    ushort* fc1o      = (ushort*)alloc((size_t)5760 * 1024 * 2);
    ushort* t2        = (ushort*)alloc((size_t)65536 * 128 * 2);
    ushort* fc1_WT    = (ushort*)alloc((size_t)1024 * 256 * 2);
    ushort* fc2_WT    = (ushort*)alloc((size_t)128 * 1024 * 2);
    ushort* bert1_WT  = (ushort*)alloc((size_t)128 * 1280 * 2);
    ushort* bert2_WT  = (ushort*)alloc((size_t)128 * 128 * 2);

    // 1. GCN + all weight transposes
    k_gcn_tr<<<NB + 560, 256, 0, stream>>>(x, ei, gW1, gb1, gW2, gb2, gW3, gb3, hd,
                                           fc1_W, fc2_W, bert1_W, bert2_W,
                                           fc1_WT, fc2_WT, bert1_WT, bert2_WT);
    // 2. bert1+bert2 fused (blocks 0..511) overlapped with fc1 (blocks 512..871)
    k_main<<<872, 256, 0, stream>>>(proteins, tgt, bert1_WT, bert1_b, bert2_WT, bert2_b,
                                    hd, fc1_WT, fc1_b, t2, fc1o);
    // 3. fc2-in-block + co-attention + head
    k_coatt_head<<<NB, 512, 0, stream>>>(t2, fc1o, fc2_WT, fc2_b,
                                         W_b, W_c, W_p, w_hc, w_hp,
                                         cat1_W, cat1_b, cat2_W, cat2_b,
                                         out_W, out_b, (float*)d_out);
}

// Round 7
// 1093.523 us; speedup vs baseline: 2.1123x; 1.0534x over previous
//
#include <hip/hip_runtime.h>
#include <hip/hip_bf16.h>

typedef __hip_bfloat16 bf16;
typedef __bf16 bf16x8 __attribute__((ext_vector_type(8)));
typedef float f32x4 __attribute__((ext_vector_type(4)));

#define NB   128   // graphs
#define NPGX 40    // nodes per graph
#define NNODE 5120 // total nodes
#define NE   20000 // edges
#define LPX  512   // protein seq len
#define MAXNX 45
#define EMAX 512   // per-graph edge cap

__device__ __forceinline__ ushort f2bf(float f) {
    uint x = __float_as_uint(f);
    return (ushort)((x + 0x7fffu + ((x >> 16) & 1u)) >> 16);
}
__device__ __forceinline__ float bf2f(ushort u) { return __uint_as_float(((uint)u) << 16); }
__device__ __forceinline__ float dot4(f32x4 a, f32x4 b) {
    return a[0]*b[0] + a[1]*b[1] + a[2]*b[2] + a[3]*b[3];
}

// =================== dispatch 1: GCN (blocks 0..127) + weight transposes (128..687) ===================
// Register-blocked gemm: f-quad fixed per thread, i iterated over j.
// W quads hoisted to regs per kk4 (reused across NQ rows); hin reads are
// (half-)wave-uniform -> LDS broadcast. Accumulation order per (i,f) unchanged (bit-exact).
template <int N, int NQ>
__device__ __forceinline__ void gcn_gemm(const float (*hin)[132], float (*hout)[260],
                                         float (*sW)[260], const float* __restrict__ Wg,
                                         int K, int t) {
    const int f = (t & (N / 4 - 1)) * 4;
    const int ibase = t / (N / 4);
    const int istep = 256 / (N / 4);
    f32x4 acc[NQ] = {};
    for (int k0 = 0; k0 < K; k0 += 32) {
        int kmax = min(32, K - k0);
        int kpad = (kmax + 3) & ~3;
        __syncthreads();
        for (int o = t; o < kpad * N; o += 256) {
            int row = o / N, c = o - row * N;
            sW[row][c] = (row < kmax) ? Wg[(k0 + row) * N + c] : 0.f;
        }
        __syncthreads();
        for (int kk = 0; kk < kpad; kk += 4) {
            f32x4 w[4];
#pragma unroll
            for (int d = 0; d < 4; d++) w[d] = *(const f32x4*)&sW[kk + d][f];
#pragma unroll
            for (int j = 0; j < NQ; j++) {
                f32x4 hv = *(const f32x4*)&hin[ibase + j * istep][k0 + kk];
#pragma unroll
                for (int d = 0; d < 4; d++) {
                    acc[j][0] = fmaf(hv[d], w[d][0], acc[j][0]);
                    acc[j][1] = fmaf(hv[d], w[d][1], acc[j][1]);
                    acc[j][2] = fmaf(hv[d], w[d][2], acc[j][2]);
                    acc[j][3] = fmaf(hv[d], w[d][3], acc[j][3]);
                }
            }
        }
    }
    __syncthreads();
#pragma unroll
    for (int j = 0; j < NQ; j++)
        *(f32x4*)&hout[ibase + j * istep][f] = acc[j];
}

__device__ __forceinline__ void gcn_agg(const float (*hout)[260], float (*hin)[132],
                                        const float* __restrict__ bias,
                                        const float* __restrict__ dgi,
                                        const int* __restrict__ rs,
                                        const int* __restrict__ colv,
                                        const float* __restrict__ valv,
                                        ushort* __restrict__ hd, int N, bool tohd, int g, int t) {
    for (int o = t; o < 40 * N; o += 256) {
        int i = o / N, f = o - i * N;
        float s = hout[i][f] * dgi[i];
        int e0 = rs[i], e1 = rs[i + 1];
        for (int e = e0; e < e1; e++) s += valv[e] * hout[colv[e]][f];
        s += bias[f];
        s = fmaxf(s, 0.f);
        if (tohd) hd[(g * MAXNX + i) * N + f] = f2bf(s);   // same rounding fc1 did during staging: bit-exact
        else      hin[i][f] = s;
    }
    if (tohd) for (int o = t; o < 5 * N; o += 256) hd[(g * MAXNX + 40) * N + o] = 0;
}

__global__ __launch_bounds__(256) void k_gcn_tr(
    const float* __restrict__ x, const int* __restrict__ ei,
    const float* __restrict__ W1, const float* __restrict__ b1,
    const float* __restrict__ W2, const float* __restrict__ b2,
    const float* __restrict__ W3, const float* __restrict__ b3,
    ushort* __restrict__ hd,
    const float* __restrict__ ws0, const float* __restrict__ ws1,
    const float* __restrict__ ws2, const float* __restrict__ ws3,
    ushort* __restrict__ wd0, ushort* __restrict__ wd1,
    ushort* __restrict__ wd2, ushort* __restrict__ wd3)
{
    __shared__ __align__(16) float hin[40][132];
    __shared__ __align__(16) float hout[40][260];
    __shared__ __align__(16) float sW[32][260];
    __shared__ int   s_cnt[40], s_cur[40], s_rs[41];
    __shared__ int   s_col[EMAX];
    __shared__ float s_val[EMAX];
    __shared__ float s_dinv[40], s_dgi[40];

    const int t = threadIdx.x;

    if (blockIdx.x >= NB) {
        float (*ts)[33] = reinterpret_cast<float(*)[33]>(&hin[0][0]);
        int bid = blockIdx.x - NB;
        const float* in; ushort* out; int K, N, b;
        if (bid < 256)      { in = ws0; out = wd0; K = 256;  N = 1024; b = bid; }        // fc1_W
        else if (bid < 384) { in = ws1; out = wd1; K = 1024; N = 128;  b = bid - 256; }  // fc2_W
        else if (bid < 544) { in = ws2; out = wd2; K = 1280; N = 128;  b = bid - 384; }  // bert1
        else                { in = ws3; out = wd3; K = 128;  N = 128;  b = bid - 544; }  // bert2
        int ktiles = K / 32;
        int kt = (b % ktiles) * 32, nt = (b / ktiles) * 32;
        int tn = t & 31, tk = t >> 5;
#pragma unroll
        for (int i = 0; i < 4; i++)
            ts[tk + i * 8][tn] = in[(long)(kt + tk + i * 8) * N + nt + tn];
        __syncthreads();
#pragma unroll
        for (int i = 0; i < 4; i++)
            out[(long)(nt + tk + i * 8) * K + kt + tn] = f2bf(ts[tn][tk + i * 8]);
        return;
    }

    const int g = blockIdx.x;
    const int base = g * NPGX;
    const int* srcp = ei;
    const int* dstp = ei + NE;

    for (int o = t; o < 40; o += 256) { s_cnt[o] = 0; s_cur[o] = 0; }
    for (int o = t; o < 40 * 78; o += 256) hin[o / 78][o % 78] = x[base * 78 + o];
    for (int o = t; o < 80; o += 256) hin[o >> 1][78 + (o & 1)] = 0.f;
    __syncthreads();
    for (int e = t; e < NE; e += 256) {
        int dl = dstp[e] - base;
        if ((unsigned)dl < 40u) atomicAdd(&s_cnt[dl], 1);
    }
    __syncthreads();
    if (t == 0) {
        int acc = 0;
        for (int i = 0; i < 40; i++) { s_rs[i] = acc; acc += s_cnt[i]; }
        s_rs[40] = acc;
    }
    if (t < 40) {
        float deg = (float)(s_cnt[t] + 1);
        s_dinv[t] = rsqrtf(deg);
        s_dgi[t] = 1.f / deg;
    }
    __syncthreads();
    for (int e = t; e < NE; e += 256) {
        int dl = dstp[e] - base;
        if ((unsigned)dl < 40u) {
            int sl = srcp[e] - base;
            int p = atomicAdd(&s_cur[dl], 1);
            int idx = s_rs[dl] + p;
            if (idx < EMAX) { s_col[idx] = sl; s_val[idx] = s_dinv[sl] * s_dinv[dl]; }
        }
    }
    __syncthreads();

    gcn_gemm<128, 5>(hin, hout, sW, W1, 78, t);
    __syncthreads();
    gcn_agg(hout, hin, b1, s_dgi, s_rs, s_col, s_val, nullptr, 128, false, g, t);
    __syncthreads();
    gcn_gemm<128, 5>(hin, hout, sW, W2, 128, t);
    __syncthreads();
    gcn_agg(hout, hin, b2, s_dgi, s_rs, s_col, s_val, nullptr, 128, false, g, t);
    __syncthreads();
    gcn_gemm<256, 10>(hin, hout, sW, W3, 128, t);
    __syncthreads();
    gcn_agg(hout, nullptr, b3, s_dgi, s_rs, s_col, s_val, hd, 256, true, g, t);
}

// =================== dispatch 2: k_main — bert1+bert2 fused (blocks 0..511) + fc1 (512..871) ===================
__global__ __launch_bounds__(256) void k_main(
    const float* __restrict__ proteins, const int* __restrict__ tgt,
    const ushort* __restrict__ bert1_WT, const float* __restrict__ bert1_b,
    const ushort* __restrict__ bert2_WT, const float* __restrict__ bert2_b,
    const ushort* __restrict__ hd, const ushort* __restrict__ fc1_WT,
    const float* __restrict__ fc1_b,
    ushort* __restrict__ t2, ushort* __restrict__ fc1o)
{
    // LDS layout: [uT1: 128x136 bf16 = 34816B (uA overlays first 10240B)][uB: 128x40 bf16 = 10240B]
    __shared__ __align__(16) char smem[45056];
    ushort (*uA)[40]   = (ushort(*)[40])smem;
    ushort (*uT1)[136] = (ushort(*)[136])smem;
    ushort (*uB)[40]   = (ushort(*)[40])(smem + 34816);

    const int t = threadIdx.x;
    const int lane = t & 63, wave = t >> 6;
    const int wr = wave >> 1, wc = wave & 1;
    const int fr = lane & 15, kh = lane >> 4;

    if (blockIdx.x < 512) {
        // ---------------- bert1 + bert2 fused ----------------
        const int m0 = blockIdx.x * 128;
        f32x4 acc[4][4] = {};
        for (int k0 = 0; k0 < 1280; k0 += 32) {
#pragma unroll
            for (int i = 0; i < 4; i++) {
                int linear = i * 1024 + t * 4;
                int row = linear >> 5, k = linear & 31;
                long gr = m0 + row;
                int bb = (int)(gr >> 9); gr = (long)tgt[bb] * LPX + (gr & 511);
                float4 v = *(const float4*)(proteins + gr * 1280L + k0 + k);
                ushort4 h;
                h.x = f2bf(v.x); h.y = f2bf(v.y); h.z = f2bf(v.z); h.w = f2bf(v.w);
                *(ushort4*)&uA[row][k] = h;
            }
#pragma unroll
            for (int i = 0; i < 2; i++) {
                int linear = i * 2048 + t * 8;
                int row = linear >> 5, k = linear & 31;
                *(uint4*)&uB[row][k] = *(const uint4*)(bert1_WT + (long)row * 1280 + k0 + k);
            }
            __syncthreads();
            bf16x8 a[4], b[4];
#pragma unroll
            for (int mf = 0; mf < 4; mf++)
                a[mf] = *(const bf16x8*)&uA[wr * 64 + mf * 16 + fr][kh * 8];
#pragma unroll
            for (int nf = 0; nf < 4; nf++)
                b[nf] = *(const bf16x8*)&uB[wc * 64 + nf * 16 + fr][kh * 8];
#pragma unroll
            for (int mf = 0; mf < 4; mf++)
#pragma unroll
                for (int nf = 0; nf < 4; nf++)
                    acc[mf][nf] = __builtin_amdgcn_mfma_f32_16x16x32_bf16(a[mf], b[nf], acc[mf][nf], 0, 0, 0);
            __syncthreads();
        }
#pragma unroll
        for (int mf = 0; mf < 4; mf++)
#pragma unroll
            for (int nf = 0; nf < 4; nf++) {
                int col = wc * 64 + nf * 16 + fr;
                float bv = bert1_b[col];
#pragma unroll
                for (int r = 0; r < 4; r++) {
                    int row = wr * 64 + mf * 16 + kh * 4 + r;
                    uT1[row][col] = f2bf(fmaxf(acc[mf][nf][r] + bv, 0.f));
                }
            }
        __syncthreads();
        // phase 2: t2 = relu(t1 @ bert2_WT^T + bert2_b)
        f32x4 acc2[4][4] = {};
        for (int ks = 0; ks < 4; ks++) {
#pragma unroll
            for (int j = 0; j < 2; j++) {
                int i2 = t + j * 256;
                int row = i2 >> 2, q = (i2 & 3) * 8;
                *(uint4*)&uB[row][q] = *(const uint4*)(bert2_WT + (long)row * 128 + ks * 32 + q);
            }
            __syncthreads();
            bf16x8 a[4], b[4];
#pragma unroll
            for (int mf = 0; mf < 4; mf++)
                a[mf] = *(const bf16x8*)&uT1[wr * 64 + mf * 16 + fr][ks * 32 + kh * 8];
#pragma unroll
            for (int nf = 0; nf < 4; nf++)
                b[nf] = *(const bf16x8*)&uB[wc * 64 + nf * 16 + fr][kh * 8];
#pragma unroll
            for (int mf = 0; mf < 4; mf++)
#pragma unroll
                for (int nf = 0; nf < 4; nf++)
                    acc2[mf][nf] = __builtin_amdgcn_mfma_f32_16x16x32_bf16(a[mf], b[nf], acc2[mf][nf], 0, 0, 0);
            __syncthreads();
        }
#pragma unroll
        for (int mf = 0; mf < 4; mf++)
#pragma unroll
            for (int nf = 0; nf < 4; nf++) {
                int col = wc * 64 + nf * 16 + fr;
                float bv = bert2_b[col];
#pragma unroll
                for (int r = 0; r < 4; r++) {
                    int row = m0 + wr * 64 + mf * 16 + kh * 4 + r;
                    t2[(long)row * 128 + col] = f2bf(fmaxf(acc2[mf][nf][r] + bv, 0.f));
                }
            }
    } else {
        // ---------------- fc1 tile: fc1o = relu(hd_bf16 @ fc1_WT^T + fc1_b) ----------------
        int ft = blockIdx.x - 512;
        const int m0 = (ft % 45) * 128;
        const int n0 = (ft / 45) * 128;
        f32x4 acc[4][4] = {};
        for (int k0 = 0; k0 < 256; k0 += 32) {
#pragma unroll
            for (int i = 0; i < 2; i++) {
                int linear = i * 2048 + t * 8;
                int row = linear >> 5, k = linear & 31;
                *(uint4*)&uA[row][k] = *(const uint4*)(hd + (long)(m0 + row) * 256 + k0 + k);
            }
#pragma unroll
            for (int i = 0; i < 2; i++) {
                int linear = i * 2048 + t * 8;
                int row = linear >> 5, k = linear & 31;
                *(uint4*)&uB[row][k] = *(const uint4*)(fc1_WT + (long)(n0 + row) * 256 + k0 + k);
            }
            __syncthreads();
            bf16x8 a[4], b[4];
#pragma unroll
            for (int mf = 0; mf < 4; mf++)
                a[mf] = *(const bf16x8*)&uA[wr * 64 + mf * 16 + fr][kh * 8];
#pragma unroll
            for (int nf = 0; nf < 4; nf++)
                b[nf] = *(const bf16x8*)&uB[wc * 64 + nf * 16 + fr][kh * 8];
#pragma unroll
            for (int mf = 0; mf < 4; mf++)
#pragma unroll
                for (int nf = 0; nf < 4; nf++)
                    acc[mf][nf] = __builtin_amdgcn_mfma_f32_16x16x32_bf16(a[mf], b[nf], acc[mf][nf], 0, 0, 0);
            __syncthreads();
        }
#pragma unroll
        for (int mf = 0; mf < 4; mf++)
#pragma unroll
            for (int nf = 0; nf < 4; nf++) {
                int col = n0 + wc * 64 + nf * 16 + fr;
                float bv = fc1_b[col];
#pragma unroll
                for (int r = 0; r < 4; r++) {
                    int row = m0 + wr * 64 + mf * 16 + kh * 4 + r;
                    fc1o[(long)row * 1024 + col] = f2bf(fmaxf(acc[mf][nf][r] + bv, 0.f));
                }
            }
    }
}

// =================== dispatch 3: fc2-in-block + co-attention + head, one block (512 thr) per graph ===================
__global__ __launch_bounds__(512) void k_coatt_head(
    const ushort* __restrict__ t2, const ushort* __restrict__ fc1o,
    const ushort* __restrict__ fc2_WT, const float* __restrict__ fc2_b,
    const float* __restrict__ W_b, const float* __restrict__ W_c,
    const float* __restrict__ W_p, const float* __restrict__ w_hc,
    const float* __restrict__ w_hp,
    const float* __restrict__ cat1_W, const float* __restrict__ cat1_b,
    const float* __restrict__ cat2_W, const float* __restrict__ cat2_b,
    const float* __restrict__ outW, const float* __restrict__ outb,
    float* __restrict__ out)
{
    __shared__ __align__(16) float  sx[48][132];    // hd2 rows (45 used; 45..47 zero)
    __shared__ __align__(16) ushort sY[48][136];
    __shared__ __align__(16) ushort sWpb[32][136];
    __shared__ __align__(16) float  sWcx[32][48];
    __shared__ __align__(16) float  sHc[32][48];
    __shared__ __align__(16) ushort sT[128][136];   // fc2 staging -> t2 chunks -> head scratch
    __shared__ __align__(16) float  sC[128][52];
    __shared__ __align__(16) float  sWpt[32][132];
    __shared__ float  sLogit[512];
    __shared__ float  sLc[64];
    __shared__ float  swh[64];
    __shared__ float  sRed[8], sRed2[8];
    __shared__ float  sPc[4][128];
    __shared__ float  sCin[256];

    const int b = blockIdx.x, tid = threadIdx.x;
    const int lane = tid & 63, wave = tid >> 6;
    const int fr = lane & 15, kh = lane >> 4;

    // ---- init ----
    for (int o = tid; o < 32 * 32; o += 512) {
        int r = o >> 5, q = (o & 31) * 4;
        f32x4 v = *(const f32x4*)&W_p[r * 128 + q];
        sWpb[r][q] = f2bf(v[0]); sWpb[r][q + 1] = f2bf(v[1]);
        sWpb[r][q + 2] = f2bf(v[2]); sWpb[r][q + 3] = f2bf(v[3]);
    }
    if (tid < 64) swh[tid] = (tid < 32) ? w_hc[tid] : w_hp[tid - 32];
    for (int o = tid; o < 32 * 12; o += 512) {
        int r = o / 12, q = (o - r * 12) * 4;
        *(f32x4*)&sHc[r][q] = f32x4{0.f, 0.f, 0.f, 0.f};
    }
    if (tid < 96) {
        int r = 45 + tid / 32, q = (tid & 31) * 4;
        *(f32x4*)&sx[r][q] = f32x4{0.f, 0.f, 0.f, 0.f};
    }

    // ---- fc2 in-block: sx[0..44][:] = relu(fc1o[b*45+s,:1024] @ fc2_WT^T + fc2_b) via MFMA ----
    {
        ushort (*sA2)[40] = (ushort(*)[40])&sT[0][0];
        ushort (*sB2)[40] = (ushort(*)[40])((char*)&sT[0][0] + 4096);
        f32x4 acc2[3] = {};
        for (int k0 = 0; k0 < 1024; k0 += 32) {
            if (tid < 192) {
                int row = tid >> 2, q = (tid & 3) * 8;
                *(uint4*)&sA2[row][q] = *(const uint4*)(fc1o + (size_t)(b * 45 + row) * 1024 + k0 + q);
            }
            {
                int row = tid >> 2, q = (tid & 3) * 8;
                *(uint4*)&sB2[row][q] = *(const uint4*)(fc2_WT + (size_t)row * 1024 + k0 + q);
            }
            __syncthreads();
            bf16x8 bfr = *(const bf16x8*)&sB2[wave * 16 + fr][kh * 8];
#pragma unroll
            for (int mf = 0; mf < 3; mf++) {
                bf16x8 afr = *(const bf16x8*)&sA2[mf * 16 + fr][kh * 8];
                acc2[mf] = __builtin_amdgcn_mfma_f32_16x16x32_bf16(afr, bfr, acc2[mf], 0, 0, 0);
            }
            __syncthreads();
        }
#pragma unroll
        for (int mf = 0; mf < 3; mf++) {
            int col = wave * 16 + fr;
            float bv = fc2_b[col];
#pragma unroll
            for (int r = 0; r < 4; r++) {
                int row = mf * 16 + kh * 4 + r;
                if (row < 45) sx[row][col] = fmaxf(acc2[mf][r] + bv, 0.f);
            }
        }
    }
    __syncthreads();

    // ---- Y[s][k] = sum_m W_b[k][m]*hd2[s][m] ----
    {
        int kg = tid >> 3, sg = tid & 7;
        float acc[12] = {};
        for (int m = 0; m < 128; m += 4) {
            f32x4 w0 = *(const f32x4*)&W_b[(2 * kg) * 128 + m];
            f32x4 w1 = *(const f32x4*)&W_b[(2 * kg + 1) * 128 + m];
#pragma unroll
            for (int u = 0; u < 6; u++) {
                f32x4 xv = *(const f32x4*)&sx[6 * sg + u][m];
                acc[u] += dot4(w0, xv);
                acc[6 + u] += dot4(w1, xv);
            }
        }
#pragma unroll
        for (int u = 0; u < 6; u++) {
            int s = 6 * sg + u;
            sY[s][2 * kg] = f2bf(acc[u]);
            sY[s][2 * kg + 1] = f2bf(acc[6 + u]);
        }
    }
    // ---- Wcx[k][s] ----
    if (tid < 256) {
        int k = tid >> 3, sg = tid & 7;
        float acc[6] = {};
        for (int m = 0; m < 128; m += 4) {
            f32x4 w = *(const f32x4*)&W_c[k * 128 + m];
#pragma unroll
            for (int u = 0; u < 6; u++) {
                f32x4 xv = *(const f32x4*)&sx[6 * sg + u][m];
                acc[u] += dot4(w, xv);
            }
        }
#pragma unroll
        for (int u = 0; u < 6; u++) sWcx[k][6 * sg + u] = acc[u];
    }
    __syncthreads();

    const ushort* t2b = t2 + ((size_t)b * 512) * 128;

    for (int lc = 0; lc < 4; lc++) {
        {
            const ushort* srcp = t2b + lc * 128 * 128;
#pragma unroll
            for (int i = 0; i < 4; i++) {
                int idx = tid + i * 512;
                int row = idx >> 4, c8 = (idx & 15) * 8;
                *(uint4*)&sT[row][c8] = *(const uint4*)(srcp + row * 128 + c8);
            }
        }
        __syncthreads();
        // MFMA: C (3 n-tiles) + Wpt (2 m-tiles)
        {
            f32x4 cacc[3] = {};
            f32x4 wacc[2] = {};
#pragma unroll
            for (int ks = 0; ks < 4; ks++) {
                bf16x8 af = *(const bf16x8*)&sT[wave * 16 + fr][ks * 32 + kh * 8];
#pragma unroll
                for (int nt = 0; nt < 3; nt++) {
                    bf16x8 bf = *(const bf16x8*)&sY[nt * 16 + fr][ks * 32 + kh * 8];
                    cacc[nt] = __builtin_amdgcn_mfma_f32_16x16x32_bf16(af, bf, cacc[nt], 0, 0, 0);
                }
#pragma unroll
                for (int mt = 0; mt < 2; mt++) {
                    bf16x8 aw = *(const bf16x8*)&sWpb[mt * 16 + fr][ks * 32 + kh * 8];
                    wacc[mt] = __builtin_amdgcn_mfma_f32_16x16x32_bf16(aw, af, wacc[mt], 0, 0, 0);
                }
            }
#pragma unroll
            for (int nt = 0; nt < 3; nt++)
#pragma unroll
                for (int r = 0; r < 4; r++)
                    sC[wave * 16 + kh * 4 + r][nt * 16 + fr] = tanhf(cacc[nt][r]);
#pragma unroll
            for (int mt = 0; mt < 2; mt++)
#pragma unroll
                for (int r = 0; r < 4; r++)
                    sWpt[mt * 16 + kh * 4 + r][wave * 16 + fr] = wacc[mt][r];
        }
        __syncthreads();
        // Hc accumulate (384 thr) + Hp partials (all threads)
        float hpacc[8];
        {
            if (tid < 384) {
                int k = tid / 12, sg = tid - (tid / 12) * 12;
                f32x4 a = {0.f, 0.f, 0.f, 0.f};
                for (int l4 = 0; l4 < 128; l4 += 4) {
                    f32x4 wv4 = *(const f32x4*)&sWpt[k][l4];
#pragma unroll
                    for (int d = 0; d < 4; d++) {
                        f32x4 cv = *(const f32x4*)&sC[l4 + d][sg * 4];
                        a[0] = fmaf(wv4[d], cv[0], a[0]); a[1] = fmaf(wv4[d], cv[1], a[1]);
                        a[2] = fmaf(wv4[d], cv[2], a[2]); a[3] = fmaf(wv4[d], cv[3], a[3]);
                    }
                }
                f32x4 h = *(const f32x4*)&sHc[k][sg * 4];
                h[0] += a[0]; h[1] += a[1]; h[2] += a[2]; h[3] += a[3];
                *(f32x4*)&sHc[k][sg * 4] = h;
            }
            int kg = tid >> 5, li = tid & 31;
            float acc[8] = {};
            for (int s4 = 0; s4 < 48; s4 += 4) {
                f32x4 w0 = *(const f32x4*)&sWcx[2 * kg][s4];
                f32x4 w1 = *(const f32x4*)&sWcx[2 * kg + 1][s4];
#pragma unroll
                for (int u = 0; u < 4; u++) {
                    f32x4 cv = *(const f32x4*)&sC[li + 32 * u][s4];
                    acc[u] += dot4(w0, cv);
                    acc[4 + u] += dot4(w1, cv);
                }
            }
#pragma unroll
            for (int u = 0; u < 8; u++) hpacc[u] = acc[u];
        }
        __syncthreads();
        // Hp in-place
        {
            int kg = tid >> 5, li = tid & 31;
#pragma unroll
            for (int u = 0; u < 4; u++) {
                sWpt[2 * kg][li + 32 * u] = tanhf(sWpt[2 * kg][li + 32 * u] + hpacc[u]);
                sWpt[2 * kg + 1][li + 32 * u] = tanhf(sWpt[2 * kg + 1][li + 32 * u] + hpacc[4 + u]);
            }
        }
        __syncthreads();
        // ap logits
        if (tid < 128) {
            float a = 0.f;
            for (int k = 0; k < 32; k++) a += swh[32 + k] * sWpt[k][tid];
            sLogit[lc * 128 + tid] = a;
        }
        __syncthreads();
    }

    // ---- Hc finalize ----
    {
        int k = tid >> 4, si = tid & 15;
        sHc[k][si] = tanhf(sWcx[k][si] + sHc[k][si]);
        sHc[k][si + 16] = tanhf(sWcx[k][si + 16] + sHc[k][si + 16]);
        sHc[k][si + 32] = tanhf(sWcx[k][si + 32] + sHc[k][si + 32]);
    }
    __syncthreads();
    if (tid < 45) {
        float a = 0.f;
        for (int k = 0; k < 32; k++) a += swh[k] * sHc[k][tid];
        sLc[tid] = a;
    }
    __syncthreads();
    if (tid < 64) {
        float v = (tid < 45) ? sLc[tid] : -1e30f;
        float mx = v;
        for (int off = 32; off; off >>= 1) mx = fmaxf(mx, __shfl_xor(mx, off));
        float e = (tid < 45) ? expf(v - mx) : 0.f;
        float sm = e;
        for (int off = 32; off; off >>= 1) sm += __shfl_xor(sm, off);
        if (tid < 45) sLc[tid] = e / sm;
    }
    __syncthreads();
    if (tid < 128) {
        float c = 0.f;
        for (int s = 0; s < 45; s++) c += sLc[s] * sx[s][tid];
        sCin[tid] = c;
    }
    // ---- ap softmax over 512 ----
    {
        float v = sLogit[tid];
        float mx = v;
        for (int off = 32; off; off >>= 1) mx = fmaxf(mx, __shfl_xor(mx, off));
        if ((tid & 63) == 0) sRed[tid >> 6] = mx;
        __syncthreads();
        mx = sRed[0];
#pragma unroll
        for (int w = 1; w < 8; w++) mx = fmaxf(mx, sRed[w]);
        float e = expf(v - mx);
        float sm = e;
        for (int off = 32; off; off >>= 1) sm += __shfl_xor(sm, off);
        if ((tid & 63) == 0) sRed2[tid >> 6] = sm;
        __syncthreads();
        sm = 0.f;
#pragma unroll
        for (int w = 0; w < 8; w++) sm += sRed2[w];
        sLogit[tid] = e / sm;
    }
    __syncthreads();
    {
        int gq = tid >> 7, m = tid & 127;
        float pp = 0.f;
        for (int l = gq * 128; l < gq * 128 + 128; l++)
            pp += sLogit[l] * bf2f(t2b[l * 128 + m]);
        sPc[gq][m] = pp;
    }
    __syncthreads();
    if (tid < 128)
        sCin[128 + tid] = sPc[0][tid] + sPc[1][tid] + sPc[2][tid] + sPc[3][tid];
    __syncthreads();

    // ---- head MLP ----
    float* sH1 = (float*)&sT[0][0];
    float* sH2 = sH1 + 1024;
#pragma unroll
    for (int j = 0; j < 2; j++) {
        int n = tid + j * 512;
        float a = cat1_b[n];
        for (int k = 0; k < 256; k++) a = fmaf(sCin[k], cat1_W[k * 1024 + n], a);
        sH1[n] = fmaxf(a, 0.f);
    }
    __syncthreads();
    {
        float a = cat2_b[tid];
        for (int k = 0; k < 1024; k++) a = fmaf(sH1[k], cat2_W[k * 512 + tid], a);
        sH2[tid] = fmaxf(a, 0.f);
    }
    __syncthreads();
    {
        float a = sH2[tid] * outW[tid];
        for (int off = 32; off; off >>= 1) a += __shfl_xor(a, off);
        if ((tid & 63) == 0) sRed[tid >> 6] = a;
        __syncthreads();
        if (tid == 0) {
            float s = 0.f;
#pragma unroll
            for (int w = 0; w < 8; w++) s += sRed[w];
            out[b] = s + outb[0];
        }
    }
}

extern "C" void kernel_launch(void* const* d_in, const int* in_sizes, int n_in,
                              void* d_out, int out_size, void* d_ws, size_t ws_size,
                              hipStream_t stream) {
    const float* x        = (const float*)d_in[0];
    const int*   ei       = (const int*)d_in[1];
    const int*   tgt      = (const int*)d_in[2];
    const float* proteins = (const float*)d_in[4];
    const float* gW1 = (const float*)d_in[5];  const float* gb1 = (const float*)d_in[6];
    const float* gW2 = (const float*)d_in[7];  const float* gb2 = (const float*)d_in[8];
    const float* gW3 = (const float*)d_in[9];  const float* gb3 = (const float*)d_in[10];
    const float* fc1_W = (const float*)d_in[11]; const float* fc1_b = (const float*)d_in[12];
    const float* fc2_W = (const float*)d_in[13]; const float* fc2_b = (const float*)d_in[14];
    const float* bert1_W = (const float*)d_in[15]; const float* bert1_b = (const float*)d_in[16];
    const float* bert2_W = (const float*)d_in[17]; const float* bert2_b = (const float*)d_in[18];
    const float* W_b = (const float*)d_in[19];
    const float* W_c = (const float*)d_in[20];
    const float* W_p = (const float*)d_in[21];
    const float* w_hc = (const float*)d_in[22];
    const float* w_hp = (const float*)d_in[23];
    const float* cat1_W = (const float*)d_in[24]; const float* cat1_b = (const float*)d_in[25];
    const float* cat2_W = (const float*)d_in[26]; const float* cat2_b = (const float*)d_in[27];
    const float* out_W = (const float*)d_in[28]; const float* out_b = (const float*)d_in[29];

    // ---- workspace layout ----
    char* w = (char*)d_ws;
    auto alloc = [&](size_t bytes) -> void* {
        void* p = (void*)w;
        w += (bytes + 255) & ~(size_t)255;
        return p;
    };
    ushort* hd        = (ushort*)alloc((size_t)5760 * 256 * 2);
    ushort* fc1o      = (ushort*)alloc((size_t)5760 * 1024 * 2);
    ushort* t2        = (ushort*)alloc((size_t)65536 * 128 * 2);
    ushort* fc1_WT    = (ushort*)alloc((size_t)1024 * 256 * 2);
    ushort* fc2_WT    = (ushort*)alloc((size_t)128 * 1024 * 2);
    ushort* bert1_WT  = (ushort*)alloc((size_t)128 * 1280 * 2);
    ushort* bert2_WT  = (ushort*)alloc((size_t)128 * 128 * 2);

    // 1. GCN (bf16 hd out) + all weight transposes
    k_gcn_tr<<<NB + 560, 256, 0, stream>>>(x, ei, gW1, gb1, gW2, gb2, gW3, gb3, hd,
                                           fc1_W, fc2_W, bert1_W, bert2_W,
                                           fc1_WT, fc2_WT, bert1_WT, bert2_WT);
    // 2. bert1+bert2 fused (blocks 0..511) overlapped with fc1 (blocks 512..871)
    k_main<<<872, 256, 0, stream>>>(proteins, tgt, bert1_WT, bert1_b, bert2_WT, bert2_b,
                                    hd, fc1_WT, fc1_b, t2, fc1o);
    // 3. fc2-in-block + co-attention + head
    k_coatt_head<<<NB, 512, 0, stream>>>(t2, fc1o, fc2_WT, fc2_b,
                                         W_b, W_c, W_p, w_hc, w_hp,
                                         cat1_W, cat1_b, cat2_W, cat2_b,
                                         out_W, out_b, (float*)d_out);
}